// Round 9
// baseline (1024.797 us; speedup 1.0000x reference)
//
#include <hip/hip_runtime.h>
#include <cstddef>

#define BB 8
#define NN 1024
#define CIN 40
#define CH 64
#define CC 128
#define COUT 9
#define KS 9
#define NL 10
#define HSTEP 0.1f
#define SKC 2   // split-K for CC matL
#define SKH 4   // split-K for CH matL

typedef __attribute__((ext_vector_type(8))) short bf16x8;
typedef __attribute__((ext_vector_type(4))) float f32x4;

__device__ __forceinline__ unsigned short f2bf(float f) {
    union { float f; unsigned u; } v;
    v.f = f;
    unsigned u = v.u;
    u += 0x7FFFu + ((u >> 16) & 1u);
    return (unsigned short)(u >> 16);
}
__device__ __forceinline__ float bf2f(unsigned short h) {
    union { unsigned u; float f; } v;
    v.u = ((unsigned)h) << 16;
    return v.f;
}

// packed-fragment address: chunk=((lb*(R/32)+row>>5)*(KDv/32)+col>>5)*2+((row>>4)&1),
// lane=((col>>3)&3)*16+(row&15), elem=col&7
__device__ __forceinline__ size_t pk_addr(int lb, int row, int col, int R, int KDv) {
    int chunk = ((lb * (R / 32) + (row >> 5)) * (KDv / 32) + (col >> 5)) * 2 + ((row >> 4) & 1);
    int lane = ((col >> 3) & 3) * 16 + (row & 15);
    return ((size_t)chunk * 64 + lane) * 8 + (col & 7);
}

// ---------------- helpers ----------------
__device__ __forceinline__ float blockSum(float v, float* red) {
    int tid = threadIdx.x;
    red[tid] = v;
    __syncthreads();
    for (int s = 128; s > 0; s >>= 1) {
        if (tid < s) red[tid] += red[tid + s];
        __syncthreads();
    }
    float r = red[0];
    __syncthreads();
    return r;
}

// ---------------- conv weights -> packed fragments directly (hi/lo) ----------------
// conv1 : row=o, col=i*16+kk (kk<9 else 0), R=CC, KDv=1024
// conv1T: row=i, col=o*16+kk with k-reversal,  R=CH, KDv=2048
__global__ __launch_bounds__(256) void k_prep_wbf(const float* __restrict__ Win,
                                                  unsigned short* __restrict__ PKc_h,
                                                  unsigned short* __restrict__ PKc_l,
                                                  unsigned short* __restrict__ PKt_h,
                                                  unsigned short* __restrict__ PKt_l) {
    int idx = blockIdx.x * 256 + threadIdx.x;
    const int total = NL * 2 * CC * CH * 16;
    if (idx >= total) return;
    int kk = idx & 15;
    int t = idx >> 4;
    int i = t % CH;  t /= CH;
    int o = t % CC;  t /= CC;
    int lb = t;
    float vc = (kk < 9) ? Win[(((size_t)lb * CC + o) * CH + i) * KS + kk] : 0.f;
    float vt = (kk < 9) ? Win[(((size_t)lb * CC + o) * CH + i) * KS + (8 - kk)] : 0.f;
    unsigned short ch = f2bf(vc);
    unsigned short th = f2bf(vt);
    size_t ac = pk_addr(lb, o, i * 16 + kk, CC, 1024);
    size_t at = pk_addr(lb, i, o * 16 + kk, CH, 2048);
    PKc_h[ac] = ch;
    PKc_l[ac] = f2bf(vc - bf2f(ch));
    PKt_h[at] = th;
    PKt_l[at] = f2bf(vt - bf2f(th));
}

// ---------------- matL W: fp32 -> packed bf16 fragments ----------------
__global__ __launch_bounds__(256) void k_wpack2(const float* __restrict__ Wg,
                                                unsigned short* __restrict__ dst) {
    int idx = blockIdx.x * 256 + threadIdx.x;
    int lane = idx & 63;
    int t = idx >> 6;
    int fn = t & 1; t >>= 1;
    int ms = t & 31; t >>= 5;
    int nt = t & 31;
    int b = t >> 5;
    int r = lane & 15, g = lane >> 4;
    const float* sp = &Wg[((size_t)b * NN + nt * 32 + fn * 16 + r) * NN + ms * 32 + g * 8];
    float v[8];
    *reinterpret_cast<float4*>(&v[0]) = *reinterpret_cast<const float4*>(sp);
    *reinterpret_cast<float4*>(&v[4]) = *reinterpret_cast<const float4*>(sp + 4);
    unsigned short* dp = dst + (size_t)idx * 8;
#pragma unroll
    for (int j = 0; j < 8; ++j) dp[j] = f2bf(v[j]);
}

// bks[lb][o][k] = sum_i Win[lb][o][i][k] * Bias[lb][i]
__global__ __launch_bounds__(256) void k_prep_bks(const float* __restrict__ Win,
                                                  const float* __restrict__ Bias,
                                                  float* __restrict__ bks) {
    int idx = blockIdx.x * 256 + threadIdx.x;
    const int total = NL * 2 * CC * KS;
    if (idx >= total) return;
    int k = idx % KS;
    int t = idx / KS;
    int o = t % CC;
    int lb = t / CC;
    float s = 0.f;
    for (int i = 0; i < CH; ++i)
        s += Win[(((size_t)lb * CC + o) * CH + i) * KS + k] * Bias[lb * CH + i];
    bks[idx] = s;
}

// ---------------- open ----------------
__global__ __launch_bounds__(256) void k_open(const float* __restrict__ Zin,
                                              const float* __restrict__ mask,
                                              const float* __restrict__ Kop,
                                              float* __restrict__ Zcur) {
    int n = blockIdx.x * 256 + threadIdx.x;
    int c = blockIdx.y, b = blockIdx.z;
    float acc = 0.f;
    for (int i = 0; i < CIN; ++i)
        acc += Kop[c * CIN + i] * Zin[((size_t)b * CIN + i) * NN + n];
    Zcur[((size_t)b * CH + c) * NN + n] = acc * mask[b * NN + n];
}

// ---------------- Za ----------------
__global__ __launch_bounds__(256) void k_za(const float* __restrict__ Zcur,
                                            const float* __restrict__ mask,
                                            float* __restrict__ Za) {
    __shared__ float red[256];
    int c = blockIdx.x;  // 0..64
    int b = blockIdx.y;
    int tid = threadIdx.x;
    const float* m = mask + b * NN;
    float x[4], mv[4];
    if (c < CH) {
        const float* src = Zcur + ((size_t)b * CH + c) * NN;
#pragma unroll
        for (int j = 0; j < 4; ++j) { int n = tid * 4 + j; x[j] = src[n]; mv[j] = m[n]; }
    } else {
#pragma unroll
        for (int j = 0; j < 4; ++j) { int n = tid * 4 + j; mv[j] = m[n]; x[j] = 0.5f * ((float)n / 1023.f) * mv[j]; }
    }
    float sm = 0.f, sxm = 0.f;
#pragma unroll
    for (int j = 0; j < 4; ++j) { sm += mv[j]; sxm += x[j] * mv[j]; }
    float msum = blockSum(sm, red);
    float xm = blockSum(sxm, red);
    if (c < CH) {
        float mean = xm / msum;
        float ss = 0.f;
#pragma unroll
        for (int j = 0; j < 4; ++j) { x[j] -= mean * mv[j]; ss += x[j] * x[j]; }
        ss = blockSum(ss, red);
        float sc = rsqrtf(ss / msum + 1e-4f);
#pragma unroll
        for (int j = 0; j < 4; ++j) x[j] *= sc;
    }
    float ps = 0.f;
#pragma unroll
    for (int j = 0; j < 4; ++j) ps += x[j];
    float pm = blockSum(ps, red) / (float)NN;
    float* dst = Za + ((size_t)b * 65 + c) * NN;
#pragma unroll
    for (int j = 0; j < 4; ++j) dst[tid * 4 + j] = x[j] - pm;
}

// ---------------- n2 ----------------
__global__ __launch_bounds__(256) void k_n2g(const float* __restrict__ Za, float* __restrict__ n2g) {
    int n = blockIdx.x * 256 + threadIdx.x;
    int b = blockIdx.y;
    float s = 0.f;
    for (int c = 0; c < 65; ++c) { float v = Za[((size_t)b * 65 + c) * NN + n]; s += v * v; }
    n2g[b * NN + n] = s;
}

// ---------------- Gram + W ----------------
__global__ __launch_bounds__(256) void k_gramW(const float* __restrict__ Za,
                                               const float* __restrict__ n2g,
                                               const float* __restrict__ mask,
                                               float* __restrict__ Wg) {
    __shared__ float As[65][64];
    __shared__ float Bs2[65][64];
    int i0 = blockIdx.x * 64, j0 = blockIdx.y * 64, b = blockIdx.z;
    int tid = threadIdx.x;
    for (int e = tid; e < 65 * 64; e += 256) {
        int c = e >> 6, t = e & 63;
        const float* src = Za + ((size_t)b * 65 + c) * NN;
        As[c][t] = src[i0 + t];
        Bs2[c][t] = src[j0 + t];
    }
    __syncthreads();
    int tx = tid & 15, ty = tid >> 4;
    float acc[4][4] = {};
    for (int c = 0; c < 65; ++c) {
        float a[4];
#pragma unroll
        for (int q = 0; q < 4; ++q) a[q] = As[c][ty * 4 + q];
        float bv[4];
        *reinterpret_cast<float4*>(bv) = *reinterpret_cast<const float4*>(&Bs2[c][tx * 4]);
#pragma unroll
        for (int q = 0; q < 4; ++q)
#pragma unroll
            for (int r = 0; r < 4; ++r) acc[q][r] += a[q] * bv[r];
    }
    const float* m = mask + b * NN;
    for (int q = 0; q < 4; ++q) {
        int i = i0 + ty * 4 + q;
        float n2i = n2g[b * NN + i], mi = m[i];
        float res[4];
#pragma unroll
        for (int r = 0; r < 4; ++r) {
            int j = j0 + tx * 4 + r;
            float D = n2i + n2g[b * NN + j] - 2.f * acc[q][r];
            D *= (3.f / 65.f);
            D = fmaxf(D, 0.f);
            float dist = (D > 0.f) ? sqrtf(D) : 0.f;
            float mmv = mi * m[j];
            res[r] = expf(-dist * mmv) * mmv;
        }
        *reinterpret_cast<float4*>(&Wg[((size_t)b * NN + i) * NN + j0 + tx * 4]) =
            *reinterpret_cast<float4*>(res);
    }
}

// ---------------- Wsum: two-phase column sums ----------------
__global__ __launch_bounds__(256) void k_wsum_part(const float* __restrict__ Wg,
                                                   float* __restrict__ Wsp) {
    int j = blockIdx.x * 256 + threadIdx.x;
    int ch = blockIdx.y;
    int b = blockIdx.z;
    float s = 0.f;
    int i0 = ch * 64;
#pragma unroll 8
    for (int i = 0; i < 64; ++i) s += Wg[((size_t)b * NN + i0 + i) * NN + j];
    Wsp[((size_t)b * 16 + ch) * NN + j] = s;
}
__global__ __launch_bounds__(256) void k_wsum_fin(const float* __restrict__ Wsp,
                                                  float* __restrict__ Wsum) {
    int j = blockIdx.x * 256 + threadIdx.x;
    int b = blockIdx.y;
    float s = 0.f;
#pragma unroll
    for (int ch = 0; ch < 16; ++ch) s += Wsp[((size_t)b * 16 + ch) * NN + j];
    Wsum[b * NN + j] = s;
}

// ---------------- MFMA implicit-GEMM conv, hi/lo bf16, packed weights ----------------
// MODE 0 (conv1, KD=1024): y=(br<<1)|o_half; mask-on-br0, bias.
// MODE 1 (conv1T, KD=2048): y=(br<<1)|kh; fused colnorm-apply ((x-mean)*mask*inv, relu)
//         during staging; partial outputs over kh.
template <int KD, int MODE>
__global__ __launch_bounds__(256) void k_conv_mfma(const float* __restrict__ InA,
                                                   const float* __restrict__ InB,
                                                   const unsigned short* __restrict__ Wh,
                                                   const unsigned short* __restrict__ Wlo,
                                                   const float* __restrict__ bksl,
                                                   const float* __restrict__ mask,
                                                   const float* __restrict__ meanA,
                                                   const float* __restrict__ invA,
                                                   float* __restrict__ OutA0,
                                                   float* __restrict__ OutA1,
                                                   float* __restrict__ OutB0,
                                                   float* __restrict__ OutB1) {
    constexpr int XW = 80;   // 64 n + 16 halo, uints
    __shared__ __align__(16) unsigned int xs[64][XW];
    int n0 = blockIdx.x * 64;
    int y = blockIdx.y;
    int b = blockIdx.z;
    int tid = threadIdx.x;
    int wid = tid >> 6, lane = tid & 63;
    int wo = (wid >> 1) * 32, wn = (wid & 1) * 32;
    int r = lane & 15, g = lane >> 4;
    int br = y >> 1, half = y & 1;

    const float* Xb;
    float* Outp;
    const float* bo_base = nullptr;
    const float* meB = nullptr;
    const float* ivB = nullptr;
    int domask = 0;
    int wtb, sg0;
    if (MODE == 0) {
        int ol = half * 64;
        Xb = InA + (size_t)b * CH * NN;
        Outp = (br ? OutB0 : OutA0) + ((size_t)b * CC + ol) * NN;
        bo_base = bksl + (br * CC + ol) * KS;
        domask = (br == 0);
        wtb = (br * 4 + half * 2 + (wid >> 1)) * 32;
        sg0 = 0;
    } else {
        int kh = half;
        Xb = (br ? InB : InA) + (size_t)b * CC * NN + (size_t)kh * 64 * NN;
        float* o0 = br ? OutB0 : OutA0;
        float* o1 = br ? OutB1 : OutA1;
        Outp = (kh ? o1 : o0) + (size_t)b * CH * NN;
        wtb = (br * 2 + (wid >> 1)) * 64;
        sg0 = kh * 32;
        meB = meanA + ((size_t)br * BB + b) * CC + kh * 64;
        ivB = invA + ((size_t)br * BB + b) * NN;
    }
    const float* mkB = mask + b * NN;

    // stage 64 rows x (64+16 halo) uints, hi/lo packed; MODE1 applies colnorm+relu
    for (int e = tid * 4; e < 64 * XW; e += 1024) {
        int i = e / XW, t = e - i * XW;
        int gn = n0 + t - 4;
        float4 v = make_float4(0.f, 0.f, 0.f, 0.f);
        if (gn >= 0 && gn + 3 < NN) {
            v = *reinterpret_cast<const float4*>(&Xb[(size_t)i * NN + gn]);
            if (MODE == 1) {
                float me = meB[i];
                float4 iv = *reinterpret_cast<const float4*>(&ivB[gn]);
                float4 mk = *reinterpret_cast<const float4*>(&mkB[gn]);
                v.x = fmaxf((v.x - me) * mk.x * iv.x, 0.f);
                v.y = fmaxf((v.y - me) * mk.y * iv.y, 0.f);
                v.z = fmaxf((v.z - me) * mk.z * iv.z, 0.f);
                v.w = fmaxf((v.w - me) * mk.w * iv.w, 0.f);
            }
        }
        uint4 u;
        unsigned short h;
        h = f2bf(v.x); u.x = (unsigned)h | ((unsigned)f2bf(v.x - bf2f(h)) << 16);
        h = f2bf(v.y); u.y = (unsigned)h | ((unsigned)f2bf(v.y - bf2f(h)) << 16);
        h = f2bf(v.z); u.z = (unsigned)h | ((unsigned)f2bf(v.z - bf2f(h)) << 16);
        h = f2bf(v.w); u.w = (unsigned)h | ((unsigned)f2bf(v.w - bf2f(h)) << 16);
        *reinterpret_cast<uint4*>(&xs[i][t]) = u;
    }
    __syncthreads();

    f32x4 acc[2][2] = {};
#pragma unroll 2
    for (int s = 0; s < 32; ++s) {
        int sg = sg0 + s;
        size_t widx = (size_t)(wtb + sg) * 1024 + lane * 8;
        bf16x8 ah[2], al[2];
        ah[0] = *reinterpret_cast<const bf16x8*>(&Wh[widx]);
        ah[1] = *reinterpret_cast<const bf16x8*>(&Wh[widx + 512]);
        al[0] = *reinterpret_cast<const bf16x8*>(&Wlo[widx]);
        al[1] = *reinterpret_cast<const bf16x8*>(&Wlo[widx + 512]);
        const unsigned int* xrow = xs[2 * s + (g >> 1)];
        int koff = (g & 1) << 3;
        bf16x8 bh[2], bl[2];
#pragma unroll
        for (int fn = 0; fn < 2; ++fn) {
            int off = wn + fn * 16 + r + koff;
            bf16x8 hh, ll;
#pragma unroll
            for (int j = 0; j < 8; ++j) {
                unsigned u = xrow[off + j];
                hh[j] = (short)(u & 0xFFFFu);
                ll[j] = (short)(u >> 16);
            }
            bh[fn] = hh;
            bl[fn] = ll;
        }
#pragma unroll
        for (int fc = 0; fc < 2; ++fc)
#pragma unroll
            for (int fn = 0; fn < 2; ++fn) {
                acc[fc][fn] = __builtin_amdgcn_mfma_f32_16x16x32_bf16(ah[fc], bh[fn], acc[fc][fn], 0, 0, 0);
                acc[fc][fn] = __builtin_amdgcn_mfma_f32_16x16x32_bf16(al[fc], bh[fn], acc[fc][fn], 0, 0, 0);
                acc[fc][fn] = __builtin_amdgcn_mfma_f32_16x16x32_bf16(ah[fc], bl[fn], acc[fc][fn], 0, 0, 0);
            }
    }

#pragma unroll
    for (int fc = 0; fc < 2; ++fc) {
#pragma unroll
        for (int fn = 0; fn < 2; ++fn) {
            int n = n0 + wn + fn * 16 + r;
#pragma unroll
            for (int rr = 0; rr < 4; ++rr) {
                int oo = wo + fc * 16 + 4 * g + rr;
                float v = acc[fc][fn][rr];
                if (MODE == 0) {
                    const float* bo = bo_base + oo * KS;
                    float bias = 0.f;
#pragma unroll
                    for (int k = 0; k < KS; ++k) {
                        int nn2 = n + k - 4;
                        if (nn2 >= 0 && nn2 < NN) bias += bo[k];
                    }
                    v += bias;
                    if (domask) v *= mkB[n];
                }
                Outp[(size_t)oo * NN + n] = v;
            }
        }
    }
}

// ---------------- MFMA split-K X@W partials (packed W, bf16 LDS A) ----------------
template <int SKN>
__global__ __launch_bounds__(256) void k_matL_mfma(const float* __restrict__ X,
                                                   const float* __restrict__ XB,
                                                   const unsigned short* __restrict__ Wpk,
                                                   float* __restrict__ Part, int rows) {
    __shared__ __align__(16) unsigned short Xs[64][36];
    int cb = rows >> 6;
    int n0 = blockIdx.x * 64;
    int sk = blockIdx.y;
    int b = blockIdx.z / cb;
    int c0 = (blockIdx.z % cb) * 64;
    int tid = threadIdx.x;
    int wid = tid >> 6, lane = tid & 63;
    int wc = (wid >> 1) * 32;
    int r = lane & 15, g = lane >> 4;
    const float* Xb = X + (size_t)b * rows * NN;
    const float* Xb2 = XB ? XB + (size_t)b * rows * NN : nullptr;
    int nt32 = blockIdx.x * 2 + (wid & 1);
    const unsigned short* Wb = Wpk + ((size_t)b * 32 + nt32) * 32 * 1024;

    int srow = tid >> 2, scol = (tid & 3) * 8;
    f32x4 acc[2][2] = {};
    int m_beg = sk * (NN / SKN);
    for (int m0 = m_beg; m0 < m_beg + NN / SKN; m0 += 32) {
        {
            const float* sp = &Xb[(size_t)(c0 + srow) * NN + m0 + scol];
            float v[8];
            *reinterpret_cast<float4*>(&v[0]) = *reinterpret_cast<const float4*>(sp);
            *reinterpret_cast<float4*>(&v[4]) = *reinterpret_cast<const float4*>(sp + 4);
            if (Xb2) {
                const float* sp2 = &Xb2[(size_t)(c0 + srow) * NN + m0 + scol];
                float w[8];
                *reinterpret_cast<float4*>(&w[0]) = *reinterpret_cast<const float4*>(sp2);
                *reinterpret_cast<float4*>(&w[4]) = *reinterpret_cast<const float4*>(sp2 + 4);
#pragma unroll
                for (int j = 0; j < 8; ++j) v[j] += w[j];
            }
            unsigned short h[8];
#pragma unroll
            for (int j = 0; j < 8; ++j) h[j] = f2bf(v[j]);
            *reinterpret_cast<ushort4*>(&Xs[srow][scol]) = *reinterpret_cast<ushort4*>(&h[0]);
            *reinterpret_cast<ushort4*>(&Xs[srow][scol + 4]) = *reinterpret_cast<ushort4*>(&h[4]);
        }
        __syncthreads();
        bf16x8 afr[2];
#pragma unroll
        for (int fc = 0; fc < 2; ++fc) {
            const uint2* p = reinterpret_cast<const uint2*>(&Xs[wc + fc * 16 + r][8 * g]);
            uint2 q0 = p[0], q1 = p[1];
            union { unsigned int u[4]; bf16x8 v; } ua;
            ua.u[0] = q0.x; ua.u[1] = q0.y; ua.u[2] = q1.x; ua.u[3] = q1.y;
            afr[fc] = ua.v;
        }
        size_t wb = (size_t)(m0 >> 5) * 1024 + lane * 8;
        bf16x8 bfr[2];
        bfr[0] = *reinterpret_cast<const bf16x8*>(&Wb[wb]);
        bfr[1] = *reinterpret_cast<const bf16x8*>(&Wb[wb + 512]);
#pragma unroll
        for (int fc = 0; fc < 2; ++fc)
#pragma unroll
            for (int fn = 0; fn < 2; ++fn)
                acc[fc][fn] = __builtin_amdgcn_mfma_f32_16x16x32_bf16(afr[fc], bfr[fn], acc[fc][fn], 0, 0, 0);
        __syncthreads();
    }
    int wn = (wid & 1) * 32;
#pragma unroll
    for (int fc = 0; fc < 2; ++fc)
#pragma unroll
        for (int fn = 0; fn < 2; ++fn) {
            int ncol = n0 + wn + fn * 16 + r;
#pragma unroll
            for (int rr = 0; rr < 4; ++rr) {
                int crow = c0 + wc + fc * 16 + 4 * g + rr;
                Part[(((size_t)b * SKN + sk) * rows + crow) * NN + ncol] = acc[fc][fn][rr];
            }
        }
}

// ---------------- reduce partials + epilogue (block = one (b,c) row) ----------------
// MODE 0: Out = (X*Wsum - sumPart)*mask ; also writes meanA[z=1] (fused A1 row-mean).
// MODE 1: Out -= H*mask*(T0A+T0B + (XA+XB)*Wsum - sumPart)
template <int SKN, int MODE>
__global__ __launch_bounds__(256) void k_matL_fin(const float* __restrict__ X,
                                                  const float* __restrict__ XB,
                                                  const float* __restrict__ Part,
                                                  const float* __restrict__ Wsum,
                                                  const float* __restrict__ mask,
                                                  const float* __restrict__ T0A,
                                                  const float* __restrict__ T0B,
                                                  float* __restrict__ Out,
                                                  float* __restrict__ meanA, int rows) {
    __shared__ float red[256];
    int c = blockIdx.x, b = blockIdx.y;
    int n = threadIdx.x * 4;
    float4 s = make_float4(0.f, 0.f, 0.f, 0.f);
#pragma unroll
    for (int sk = 0; sk < SKN; ++sk) {
        float4 p = *reinterpret_cast<const float4*>(
            &Part[(((size_t)b * SKN + sk) * rows + c) * NN + n]);
        s.x += p.x; s.y += p.y; s.z += p.z; s.w += p.w;
    }
    float4 xv = *reinterpret_cast<const float4*>(&X[((size_t)b * rows + c) * NN + n]);
    if (XB) {
        float4 x2 = *reinterpret_cast<const float4*>(&XB[((size_t)b * rows + c) * NN + n]);
        xv.x += x2.x; xv.y += x2.y; xv.z += x2.z; xv.w += x2.w;
    }
    float4 wv = *reinterpret_cast<const float4*>(&Wsum[b * NN + n]);
    float4 mv = *reinterpret_cast<const float4*>(&mask[b * NN + n]);
    float y0 = xv.x * wv.x - s.x, y1 = xv.y * wv.y - s.y;
    float y2 = xv.z * wv.z - s.z, y3 = xv.w * wv.w - s.w;
    if (MODE == 0) {
        float4 res = make_float4(y0 * mv.x, y1 * mv.y, y2 * mv.z, y3 * mv.w);
        *reinterpret_cast<float4*>(&Out[((size_t)b * rows + c) * NN + n]) = res;
        float rs = res.x * mv.x + res.y * mv.y + res.z * mv.z + res.w * mv.w;
        float ms = mv.x + mv.y + mv.z + mv.w;
        rs = blockSum(rs, red);
        ms = blockSum(ms, red);
        if (threadIdx.x == 0) meanA[((size_t)BB + b) * CC + c] = rs / ms;
    } else {
        float4 t0 = *reinterpret_cast<const float4*>(&T0A[((size_t)b * rows + c) * NN + n]);
        float4 t0b = *reinterpret_cast<const float4*>(&T0B[((size_t)b * rows + c) * NN + n]);
        t0.x += t0b.x; t0.y += t0b.y; t0.z += t0b.z; t0.w += t0b.w;
        float4 o = *reinterpret_cast<const float4*>(&Out[((size_t)b * rows + c) * NN + n]);
        float4 res = make_float4(o.x - HSTEP * mv.x * (t0.x + y0),
                                 o.y - HSTEP * mv.y * (t0.y + y1),
                                 o.z - HSTEP * mv.z * (t0.z + y2),
                                 o.w - HSTEP * mv.w * (t0.w + y3));
        *reinterpret_cast<float4*>(&Out[((size_t)b * rows + c) * NN + n]) = res;
    }
}

// ---------------- masked row mean (C0 only, z=0) ----------------
__global__ __launch_bounds__(256) void k_rowmean(const float* __restrict__ X0,
                                                 const float* __restrict__ mask,
                                                 float* __restrict__ meanA) {
    __shared__ float red[256];
    int c = blockIdx.x, b = blockIdx.y, tid = threadIdx.x;
    const float* src = X0 + ((size_t)b * CC + c) * NN;
    const float* m = mask + b * NN;
    float s = 0.f, sm = 0.f;
    for (int n = tid; n < NN; n += 256) { float mv = m[n]; s += src[n] * mv; sm += mv; }
    float ts = blockSum(s, red);
    float tm = blockSum(sm, red);
    if (tid == 0) meanA[(size_t)b * CC + c] = ts / tm;
}

// ---------------- colnorm inv only (no write-back of X) ----------------
__global__ __launch_bounds__(256) void k_colnorm_inv(const float* __restrict__ X0,
                                                     const float* __restrict__ X1,
                                                     const float* __restrict__ mask,
                                                     const float* __restrict__ meanA,
                                                     float* __restrict__ invA) {
    __shared__ float red[8][32];
    int tid = threadIdx.x;
    int nl = tid & 31, cg = tid >> 5;
    int n = blockIdx.x * 32 + nl;
    int b = blockIdx.y, z = blockIdx.z;
    const float* X = (z ? X1 : X0) + (size_t)b * CC * NN;
    const float* me = meanA + ((size_t)z * BB + b) * CC;
    float mv = mask[b * NN + n];
    float ss = 0.f;
#pragma unroll
    for (int cc = 0; cc < 16; ++cc) {
        int c = cg * 16 + cc;
        float v = (X[(size_t)c * NN + n] - me[c]) * mv;
        ss += v * v;
    }
    red[cg][nl] = ss;
    __syncthreads();
    if (cg < 4) red[cg][nl] += red[cg + 4][nl];
    __syncthreads();
    if (cg < 2) red[cg][nl] += red[cg + 2][nl];
    __syncthreads();
    if (cg < 1) red[0][nl] += red[1][nl];
    __syncthreads();
    if (cg == 0) invA[((size_t)z * BB + b) * NN + n] = rsqrtf(red[0][nl] + 0.001f);
}

// ---------------- close (64n x 4 c-groups) ----------------
__global__ __launch_bounds__(256) void k_close(const float* __restrict__ Zcur,
                                               const float* __restrict__ Kcl,
                                               const float* __restrict__ mask,
                                               float* __restrict__ Zout) {
    __shared__ float red[4][64][COUT];
    int tid = threadIdx.x;
    int nl = tid & 63, cg = tid >> 6;
    int n = blockIdx.x * 64 + nl;
    int b = blockIdx.y;
    float acc[COUT] = {};
#pragma unroll
    for (int cc = 0; cc < 16; ++cc) {
        int c = cg * 16 + cc;
        float zv = Zcur[((size_t)b * CH + c) * NN + n];
#pragma unroll
        for (int o = 0; o < COUT; ++o) acc[o] += Kcl[o * CH + c] * zv;
    }
#pragma unroll
    for (int o = 0; o < COUT; ++o) red[cg][nl][o] = acc[o];
    __syncthreads();
    if (cg == 0) {
        float mv = mask[b * NN + n];
#pragma unroll
        for (int o = 0; o < COUT; ++o) {
            float s = red[0][nl][o] + red[1][nl][o] + red[2][nl][o] + red[3][nl][o];
            Zout[((size_t)b * COUT + o) * NN + n] = s * mv;
        }
    }
}

// ---------------- center3 ----------------
__global__ __launch_bounds__(256) void k_center3(const float* __restrict__ Zout, float* __restrict__ Zc3) {
    __shared__ float red[256];
    int c = blockIdx.x, b = blockIdx.y, tid = threadIdx.x;
    const float* src = Zout + ((size_t)b * COUT + c) * NN;
    float s = 0.f;
    for (int n = tid; n < NN; n += 256) s += src[n];
    float mean = blockSum(s, red) / (float)NN;
    float* dst = Zc3 + ((size_t)b * COUT + c) * NN;
    for (int n = tid; n < NN; n += 256) dst[n] = src[n] - mean;
}

__global__ __launch_bounds__(256) void k_n23(const float* __restrict__ Zc3, float* __restrict__ n23) {
    int n = blockIdx.x * 256 + threadIdx.x;
    int g = blockIdx.y, b = blockIdx.z;
    float s = 0.f;
#pragma unroll
    for (int c = 0; c < 3; ++c) { float v = Zc3[((size_t)b * COUT + g * 3 + c) * NN + n]; s += v * v; }
    n23[((size_t)b * 3 + g) * NN + n] = s;
}

// ---------------- final pairwise distances ----------------
__global__ __launch_bounds__(256) void k_dist(const float* __restrict__ Zc3,
                                              const float* __restrict__ n23,
                                              float* __restrict__ dout) {
    __shared__ float Ai[3][64], Aj[3][64], ni[64], nj[64];
    int bg = blockIdx.z;
    int b = bg / 3, g = bg - 3 * b;
    int i0 = blockIdx.x * 64, j0 = blockIdx.y * 64;
    int tid = threadIdx.x;
    if (tid < 64) ni[tid] = n23[((size_t)b * 3 + g) * NN + i0 + tid];
    else if (tid < 128) { int t = tid - 64; nj[t] = n23[((size_t)b * 3 + g) * NN + j0 + t]; }
    for (int e = tid; e < 192; e += 256) {
        int c = e / 64, t = e - c * 64;
        Ai[c][t] = Zc3[((size_t)b * COUT + g * 3 + c) * NN + i0 + t];
    }
    for (int e = tid; e < 192; e += 256) {
        int c = e / 64, t = e - c * 64;
        Aj[c][t] = Zc3[((size_t)b * COUT + g * 3 + c) * NN + j0 + t];
    }
    __syncthreads();
    int tx = tid & 15, ty = tid >> 4;
    for (int q = 0; q < 4; ++q) {
        int i = ty * 4 + q;
        float a0 = Ai[0][i], a1 = Ai[1][i], a2 = Ai[2][i], n2i = ni[i];
        float res[4];
#pragma unroll
        for (int r = 0; r < 4; ++r) {
            int j = tx * 4 + r;
            float D = n2i + nj[j] - 2.f * (a0 * Aj[0][j] + a1 * Aj[1][j] + a2 * Aj[2][j]);
            D = fmaxf(D, 0.f);
            res[r] = (D > 0.f) ? sqrtf(D) : 0.f;
        }
        *reinterpret_cast<float4*>(&dout[(((size_t)b * 3 + g) * NN + i0 + i) * NN + j0 + tx * 4]) =
            *reinterpret_cast<float4*>(res);
    }
}

// ---------------- driver ----------------
extern "C" void kernel_launch(void* const* d_in, const int* in_sizes, int n_in,
                              void* d_out, int out_size, void* d_ws, size_t ws_size,
                              hipStream_t stream) {
    (void)in_sizes; (void)n_in; (void)out_size; (void)ws_size;
    const float* Zin  = (const float*)d_in[0];
    const float* mask = (const float*)d_in[1];
    const float* Kop  = (const float*)d_in[2];
    const float* Kcl  = (const float*)d_in[3];
    const float* Win  = (const float*)d_in[4];
    const float* Bias = (const float*)d_in[5];
    float* out = (float*)d_out;
    float* ws = (float*)d_ws;

    size_t off = 0;
    float* Zcur = ws + off;  off += (size_t)BB * CH * NN;
    float* C0   = ws + off;  off += (size_t)BB * CC * NN;
    float* C1   = ws + off;  off += (size_t)BB * CC * NN;
    float* A1   = ws + off;  off += (size_t)BB * CC * NN;
    float* T0A  = ws + off;  off += (size_t)BB * CH * NN;
    float* T1pA = ws + off;  off += (size_t)BB * CH * NN;
    float* Za   = ws + off;  off += (size_t)BB * 65 * NN;
    float* n2g  = ws + off;  off += (size_t)BB * NN;
    float* Wg   = ws + off;  off += (size_t)BB * NN * NN;
    float* Wsum = ws + off;  off += (size_t)BB * NN;
    float* meanA= ws + off;  off += (size_t)2 * BB * CC;
    float* bks  = ws + off;  off += (size_t)NL * 2 * CC * KS;
    float* Zc3  = ws + off;  off += (size_t)BB * COUT * NN;
    float* n23  = ws + off;  off += (size_t)BB * 3 * NN;
    float* Wsp  = ws + off;  off += (size_t)BB * 16 * NN;
    float* invA = ws + off;  off += (size_t)2 * BB * NN;

    // Scratch in the (as-yet-unwritten) dists region of d_out (25,165,824 floats):
    float* Part = out;                                                   // [0 .. 2,097,152) used
    unsigned short* Wpk2  = (unsigned short*)(out + (size_t)4194304);    // matL packed W
    float* T0B  = out + (size_t)13631488;
    float* T1pB = out + (size_t)14155776;
    unsigned short* PKc_h = (unsigned short*)(out + (size_t)14680064);   // packed conv weights
    unsigned short* PKc_l = (unsigned short*)(out + (size_t)15990784);
    unsigned short* PKt_h = (unsigned short*)(out + (size_t)17301504);
    unsigned short* PKt_l = (unsigned short*)(out + (size_t)18612224);

    const int wtot = NL * 2 * CC * CH * 16;
    k_prep_wbf<<<dim3((wtot + 255) / 256), 256, 0, stream>>>(Win, PKc_h, PKc_l, PKt_h, PKt_l);
    k_prep_bks<<<dim3((NL * 2 * CC * KS + 255) / 256), 256, 0, stream>>>(Win, Bias, bks);
    k_open<<<dim3(NN / 256, CH, BB), 256, 0, stream>>>(Zin, mask, Kop, Zcur);
    k_za<<<dim3(65, BB), 256, 0, stream>>>(Zcur, mask, Za);
    k_n2g<<<dim3(NN / 256, BB), 256, 0, stream>>>(Za, n2g);
    k_gramW<<<dim3(16, 16, BB), 256, 0, stream>>>(Za, n2g, mask, Wg);
    k_wsum_part<<<dim3(NN / 256, 16, BB), 256, 0, stream>>>(Wg, Wsp);
    k_wsum_fin<<<dim3(NN / 256, BB), 256, 0, stream>>>(Wsp, Wsum);
    k_wpack2<<<dim3((int)((size_t)BB * NN * NN / 8 / 256)), 256, 0, stream>>>(Wg, Wpk2);

    for (int l = 0; l < NL; ++l) {
        const unsigned short* PKc_h_l = PKc_h + (size_t)l * 2 * CC * 1024;
        const unsigned short* PKc_l_l = PKc_l + (size_t)l * 2 * CC * 1024;
        const unsigned short* PKt_h_l = PKt_h + (size_t)l * 2 * CH * 2048;
        const unsigned short* PKt_l_l = PKt_l + (size_t)l * 2 * CH * 2048;
        const float* bksl = bks + (size_t)l * 2 * CC * KS;

        k_conv_mfma<1024, 0><<<dim3(NN / 64, 4, BB), 256, 0, stream>>>(
            Zcur, nullptr, PKc_h_l, PKc_l_l, bksl, mask, nullptr, nullptr,
            C0, nullptr, C1, nullptr);
        k_matL_mfma<SKC><<<dim3(NN / 64, SKC, BB * (CC / 64)), 256, 0, stream>>>(C1, nullptr, Wpk2, Part, CC);
        k_matL_fin<SKC, 0><<<dim3(CC, BB), 256, 0, stream>>>(
            C1, nullptr, Part, Wsum, mask, nullptr, nullptr, A1, meanA, CC);
        k_rowmean<<<dim3(CC, BB), 256, 0, stream>>>(C0, mask, meanA);
        k_colnorm_inv<<<dim3(NN / 32, BB, 2), 256, 0, stream>>>(C0, A1, mask, meanA, invA);
        k_conv_mfma<2048, 1><<<dim3(NN / 64, 4, BB), 256, 0, stream>>>(
            C0, A1, PKt_h_l, PKt_l_l, nullptr, mask, meanA, invA,
            T0A, T0B, T1pA, T1pB);
        k_matL_mfma<SKH><<<dim3(NN / 64, SKH, BB * (CH / 64)), 256, 0, stream>>>(T1pA, T1pB, Wpk2, Part, CH);
        k_matL_fin<SKH, 1><<<dim3(CH, BB), 256, 0, stream>>>(
            T1pA, T1pB, Part, Wsum, mask, T0A, T0B, Zcur, nullptr, CH);
    }

    float* Zout = out + (size_t)BB * 3 * NN * NN;
    k_close<<<dim3(NN / 64, BB), 256, 0, stream>>>(Zcur, Kcl, mask, Zout);
    k_center3<<<dim3(COUT, BB), 256, 0, stream>>>(Zout, Zc3);
    k_n23<<<dim3(NN / 256, 3, BB), 256, 0, stream>>>(Zc3, n23);
    k_dist<<<dim3(16, 16, 3 * BB), 256, 0, stream>>>(Zc3, n23, out);
}

// Round 11
// 952.175 us; speedup vs baseline: 1.0763x; 1.0763x over previous
//
#include <hip/hip_runtime.h>
#include <cstddef>

#define BB 8
#define NN 1024
#define CIN 40
#define CH 64
#define CC 128
#define COUT 9
#define KS 9
#define NL 10
#define HSTEP 0.1f
#define SKC 2   // split-K for CC matL
#define SKH 4   // split-K for CH matL

typedef __attribute__((ext_vector_type(8))) short bf16x8;
typedef __attribute__((ext_vector_type(4))) float f32x4;

__device__ __forceinline__ unsigned short f2bf(float f) {
    union { float f; unsigned u; } v;
    v.f = f;
    unsigned u = v.u;
    u += 0x7FFFu + ((u >> 16) & 1u);
    return (unsigned short)(u >> 16);
}
__device__ __forceinline__ float bf2f(unsigned short h) {
    union { unsigned u; float f; } v;
    v.u = ((unsigned)h) << 16;
    return v.f;
}

// packed-fragment address (chunk = 64 lanes x 8 shorts = 512):
// chunk=((lb*(R/32)+row>>5)*(KDv/32)+col>>5)*2+((row>>4)&1), lane=((col>>3)&3)*16+(row&15)
__device__ __forceinline__ size_t pk_addr(int lb, int row, int col, int R, int KDv) {
    int chunk = ((lb * (R / 32) + (row >> 5)) * (KDv / 32) + (col >> 5)) * 2 + ((row >> 4) & 1);
    int lane = ((col >> 3) & 3) * 16 + (row & 15);
    return ((size_t)chunk * 64 + lane) * 8 + (col & 7);
}

// ---------------- helpers ----------------
__device__ __forceinline__ float blockSum(float v, float* red) {
    int tid = threadIdx.x;
    red[tid] = v;
    __syncthreads();
    for (int s = 128; s > 0; s >>= 1) {
        if (tid < s) red[tid] += red[tid + s];
        __syncthreads();
    }
    float r = red[0];
    __syncthreads();
    return r;
}

// ---------------- conv weights -> packed fragments, k-major contraction, hi/lo ----------------
// conv1 : row=o, col=k*64+i,           R=CC, KDv=576
// conv1T: row=i, col=(8-k)*128+o,      R=CH, KDv=1152
__global__ __launch_bounds__(256) void k_prep_wbf(const float* __restrict__ Win,
                                                  unsigned short* __restrict__ PKc_h,
                                                  unsigned short* __restrict__ PKc_l,
                                                  unsigned short* __restrict__ PKt_h,
                                                  unsigned short* __restrict__ PKt_l) {
    int idx = blockIdx.x * 256 + threadIdx.x;
    const int total = NL * 2 * CC * CH * KS;
    if (idx >= total) return;
    int k = idx % KS;
    int t = idx / KS;
    int i = t % CH;  t /= CH;
    int o = t % CC;  t /= CC;
    int lb = t;
    float v = Win[idx];
    unsigned short h = f2bf(v);
    unsigned short l = f2bf(v - bf2f(h));
    size_t ac = pk_addr(lb, o, k * 64 + i, CC, 576);
    size_t at = pk_addr(lb, i, (8 - k) * 128 + o, CH, 1152);
    PKc_h[ac] = h;
    PKc_l[ac] = l;
    PKt_h[at] = h;
    PKt_l[at] = l;
}

// ---------------- matL W: fp32 -> packed bf16 fragments ----------------
__global__ __launch_bounds__(256) void k_wpack2(const float* __restrict__ Wg,
                                                unsigned short* __restrict__ dst) {
    int idx = blockIdx.x * 256 + threadIdx.x;
    int lane = idx & 63;
    int t = idx >> 6;
    int fn = t & 1; t >>= 1;
    int ms = t & 31; t >>= 5;
    int nt = t & 31;
    int b = t >> 5;
    int r = lane & 15, g = lane >> 4;
    const float* sp = &Wg[((size_t)b * NN + nt * 32 + fn * 16 + r) * NN + ms * 32 + g * 8];
    float v[8];
    *reinterpret_cast<float4*>(&v[0]) = *reinterpret_cast<const float4*>(sp);
    *reinterpret_cast<float4*>(&v[4]) = *reinterpret_cast<const float4*>(sp + 4);
    unsigned short* dp = dst + (size_t)idx * 8;
#pragma unroll
    for (int j = 0; j < 8; ++j) dp[j] = f2bf(v[j]);
}

// bks[lb][o][k] = sum_i Win[lb][o][i][k] * Bias[lb][i]
__global__ __launch_bounds__(256) void k_prep_bks(const float* __restrict__ Win,
                                                  const float* __restrict__ Bias,
                                                  float* __restrict__ bks) {
    int idx = blockIdx.x * 256 + threadIdx.x;
    const int total = NL * 2 * CC * KS;
    if (idx >= total) return;
    int k = idx % KS;
    int t = idx / KS;
    int o = t % CC;
    int lb = t / CC;
    float s = 0.f;
    for (int i = 0; i < CH; ++i)
        s += Win[(((size_t)lb * CC + o) * CH + i) * KS + k] * Bias[lb * CH + i];
    bks[idx] = s;
}

// ---------------- open ----------------
__global__ __launch_bounds__(256) void k_open(const float* __restrict__ Zin,
                                              const float* __restrict__ mask,
                                              const float* __restrict__ Kop,
                                              float* __restrict__ Zcur) {
    int n = blockIdx.x * 256 + threadIdx.x;
    int c = blockIdx.y, b = blockIdx.z;
    float acc = 0.f;
    for (int i = 0; i < CIN; ++i)
        acc += Kop[c * CIN + i] * Zin[((size_t)b * CIN + i) * NN + n];
    Zcur[((size_t)b * CH + c) * NN + n] = acc * mask[b * NN + n];
}

// ---------------- Za ----------------
__global__ __launch_bounds__(256) void k_za(const float* __restrict__ Zcur,
                                            const float* __restrict__ mask,
                                            float* __restrict__ Za) {
    __shared__ float red[256];
    int c = blockIdx.x;  // 0..64
    int b = blockIdx.y;
    int tid = threadIdx.x;
    const float* m = mask + b * NN;
    float x[4], mv[4];
    if (c < CH) {
        const float* src = Zcur + ((size_t)b * CH + c) * NN;
#pragma unroll
        for (int j = 0; j < 4; ++j) { int n = tid * 4 + j; x[j] = src[n]; mv[j] = m[n]; }
    } else {
#pragma unroll
        for (int j = 0; j < 4; ++j) { int n = tid * 4 + j; mv[j] = m[n]; x[j] = 0.5f * ((float)n / 1023.f) * mv[j]; }
    }
    float sm = 0.f, sxm = 0.f;
#pragma unroll
    for (int j = 0; j < 4; ++j) { sm += mv[j]; sxm += x[j] * mv[j]; }
    float msum = blockSum(sm, red);
    float xm = blockSum(sxm, red);
    if (c < CH) {
        float mean = xm / msum;
        float ss = 0.f;
#pragma unroll
        for (int j = 0; j < 4; ++j) { x[j] -= mean * mv[j]; ss += x[j] * x[j]; }
        ss = blockSum(ss, red);
        float sc = rsqrtf(ss / msum + 1e-4f);
#pragma unroll
        for (int j = 0; j < 4; ++j) x[j] *= sc;
    }
    float ps = 0.f;
#pragma unroll
    for (int j = 0; j < 4; ++j) ps += x[j];
    float pm = blockSum(ps, red) / (float)NN;
    float* dst = Za + ((size_t)b * 65 + c) * NN;
#pragma unroll
    for (int j = 0; j < 4; ++j) dst[tid * 4 + j] = x[j] - pm;
}

// ---------------- n2 ----------------
__global__ __launch_bounds__(256) void k_n2g(const float* __restrict__ Za, float* __restrict__ n2g) {
    int n = blockIdx.x * 256 + threadIdx.x;
    int b = blockIdx.y;
    float s = 0.f;
    for (int c = 0; c < 65; ++c) { float v = Za[((size_t)b * 65 + c) * NN + n]; s += v * v; }
    n2g[b * NN + n] = s;
}

// ---------------- Gram + W ----------------
__global__ __launch_bounds__(256) void k_gramW(const float* __restrict__ Za,
                                               const float* __restrict__ n2g,
                                               const float* __restrict__ mask,
                                               float* __restrict__ Wg) {
    __shared__ float As[65][64];
    __shared__ float Bs2[65][64];
    int i0 = blockIdx.x * 64, j0 = blockIdx.y * 64, b = blockIdx.z;
    int tid = threadIdx.x;
    for (int e = tid; e < 65 * 64; e += 256) {
        int c = e >> 6, t = e & 63;
        const float* src = Za + ((size_t)b * 65 + c) * NN;
        As[c][t] = src[i0 + t];
        Bs2[c][t] = src[j0 + t];
    }
    __syncthreads();
    int tx = tid & 15, ty = tid >> 4;
    float acc[4][4] = {};
    for (int c = 0; c < 65; ++c) {
        float a[4];
#pragma unroll
        for (int q = 0; q < 4; ++q) a[q] = As[c][ty * 4 + q];
        float bv[4];
        *reinterpret_cast<float4*>(bv) = *reinterpret_cast<const float4*>(&Bs2[c][tx * 4]);
#pragma unroll
        for (int q = 0; q < 4; ++q)
#pragma unroll
            for (int r = 0; r < 4; ++r) acc[q][r] += a[q] * bv[r];
    }
    const float* m = mask + b * NN;
    for (int q = 0; q < 4; ++q) {
        int i = i0 + ty * 4 + q;
        float n2i = n2g[b * NN + i], mi = m[i];
        float res[4];
#pragma unroll
        for (int r = 0; r < 4; ++r) {
            int j = j0 + tx * 4 + r;
            float D = n2i + n2g[b * NN + j] - 2.f * acc[q][r];
            D *= (3.f / 65.f);
            D = fmaxf(D, 0.f);
            float dist = (D > 0.f) ? sqrtf(D) : 0.f;
            float mmv = mi * m[j];
            res[r] = expf(-dist * mmv) * mmv;
        }
        *reinterpret_cast<float4*>(&Wg[((size_t)b * NN + i) * NN + j0 + tx * 4]) =
            *reinterpret_cast<float4*>(res);
    }
}

// ---------------- Wsum: two-phase column sums ----------------
__global__ __launch_bounds__(256) void k_wsum_part(const float* __restrict__ Wg,
                                                   float* __restrict__ Wsp) {
    int j = blockIdx.x * 256 + threadIdx.x;
    int ch = blockIdx.y;
    int b = blockIdx.z;
    float s = 0.f;
    int i0 = ch * 64;
#pragma unroll 8
    for (int i = 0; i < 64; ++i) s += Wg[((size_t)b * NN + i0 + i) * NN + j];
    Wsp[((size_t)b * 16 + ch) * NN + j] = s;
}
__global__ __launch_bounds__(256) void k_wsum_fin(const float* __restrict__ Wsp,
                                                  float* __restrict__ Wsum) {
    int j = blockIdx.x * 256 + threadIdx.x;
    int b = blockIdx.y;
    float s = 0.f;
#pragma unroll
    for (int ch = 0; ch < 16; ++ch) s += Wsp[((size_t)b * 16 + ch) * NN + j];
    Wsum[b * NN + j] = s;
}

// ---------------- conv1 (k-major MFMA): block 64o x 64n, y=(br,o_half), K=9k x 64ch ----------------
__global__ __launch_bounds__(256) void k_conv1_mfma(const float* __restrict__ Zcur,
                                                    const unsigned short* __restrict__ Wh,
                                                    const unsigned short* __restrict__ Wl,
                                                    const float* __restrict__ bksl,
                                                    const float* __restrict__ mask,
                                                    float* __restrict__ C0,
                                                    float* __restrict__ C1) {
    __shared__ __align__(16) unsigned short xh[80][64];
    __shared__ __align__(16) unsigned short xl[80][64];
    int n0 = blockIdx.x * 64;
    int y = blockIdx.y;
    int b = blockIdx.z;
    int br = y >> 1, half = y & 1;
    int tid = threadIdx.x;
    const float* Xb = Zcur + (size_t)b * CH * NN;

    // stage transposed hi/lo with XOR swizzle: xs[row n'][ch ^ ((n'&7)<<3)]
    for (int e = tid; e < 64 * 20; e += 256) {
        int i = e / 20, t = e - i * 20;
        int gn = n0 + t * 4 - 4;
        float4 v = make_float4(0.f, 0.f, 0.f, 0.f);
        if (gn >= 0 && gn + 3 < NN) v = *reinterpret_cast<const float4*>(&Xb[(size_t)i * NN + gn]);
        float vv[4] = {v.x, v.y, v.z, v.w};
#pragma unroll
        for (int j = 0; j < 4; ++j) {
            int row = t * 4 + j;
            int col = i ^ ((row & 7) << 3);
            unsigned short h = f2bf(vv[j]);
            xh[row][col] = h;
            xl[row][col] = f2bf(vv[j] - bf2f(h));
        }
    }
    __syncthreads();

    int wid = tid >> 6, lane = tid & 63;
    int wo = (wid >> 1) * 32, wn = (wid & 1) * 32;
    int r = lane & 15, g = lane >> 4;
    int r32 = half * 2 + (wid >> 1);  // o-row-tile within branch (R=128)
    size_t brOff = (size_t)br * (CC / 32) * (576 / 32) * 1024;

    f32x4 acc[2][2] = {};
#pragma unroll 3
    for (int q = 0; q < 18; ++q) {
        int k = q >> 1, s = q & 1;
        size_t widx = brOff + ((size_t)(r32 * 18 + q)) * 1024 + lane * 8;
        bf16x8 ah[2], al[2];
        ah[0] = *reinterpret_cast<const bf16x8*>(&Wh[widx]);
        ah[1] = *reinterpret_cast<const bf16x8*>(&Wh[widx + 512]);
        al[0] = *reinterpret_cast<const bf16x8*>(&Wl[widx]);
        al[1] = *reinterpret_cast<const bf16x8*>(&Wl[widx + 512]);
        bf16x8 bh[2], bl[2];
#pragma unroll
        for (int fn = 0; fn < 2; ++fn) {
            int row = wn + fn * 16 + r + k;
            int chs = (s * 32 + g * 8) ^ ((row & 7) << 3);
            bh[fn] = *reinterpret_cast<const bf16x8*>(&xh[row][chs]);
            bl[fn] = *reinterpret_cast<const bf16x8*>(&xl[row][chs]);
        }
#pragma unroll
        for (int fc = 0; fc < 2; ++fc)
#pragma unroll
            for (int fn = 0; fn < 2; ++fn) {
                acc[fc][fn] = __builtin_amdgcn_mfma_f32_16x16x32_bf16(ah[fc], bh[fn], acc[fc][fn], 0, 0, 0);
                acc[fc][fn] = __builtin_amdgcn_mfma_f32_16x16x32_bf16(al[fc], bh[fn], acc[fc][fn], 0, 0, 0);
                acc[fc][fn] = __builtin_amdgcn_mfma_f32_16x16x32_bf16(ah[fc], bl[fn], acc[fc][fn], 0, 0, 0);
            }
    }

    const float* mkB = mask + b * NN;
    float* Outp = (br ? C1 : C0) + ((size_t)b * CC + half * 64) * NN;
    const float* bo_base = bksl + (br * CC + half * 64) * KS;
#pragma unroll
    for (int fc = 0; fc < 2; ++fc) {
#pragma unroll
        for (int fn = 0; fn < 2; ++fn) {
            int n = n0 + wn + fn * 16 + r;
#pragma unroll
            for (int rr = 0; rr < 4; ++rr) {
                int oo = wo + fc * 16 + 4 * g + rr;
                float v = acc[fc][fn][rr];
                const float* bo = bo_base + oo * KS;
                float bias = 0.f;
#pragma unroll
                for (int k = 0; k < KS; ++k) {
                    int nn2 = n + k - 4;
                    if (nn2 >= 0 && nn2 < NN) bias += bo[k];
                }
                v += bias;
                if (br == 0) v *= mkB[n];
                Outp[(size_t)oo * NN + n] = v;
            }
        }
    }
}

// ---------------- conv1T (k-major MFMA): block 64i x 32n, y=br; in-block split-K ----------------
// Staging applies colnorm: relu((x - mean)*mask*inv). Outputs single T (no partials).
__global__ __launch_bounds__(256) void k_convT_mfma(const float* __restrict__ C0,
                                                    const float* __restrict__ A1,
                                                    const unsigned short* __restrict__ Wh,
                                                    const unsigned short* __restrict__ Wl,
                                                    const float* __restrict__ mask,
                                                    const float* __restrict__ meanA,
                                                    const float* __restrict__ invA,
                                                    float* __restrict__ T0,
                                                    float* __restrict__ T1p) {
    __shared__ __align__(16) unsigned short xh[48][128];
    __shared__ __align__(16) unsigned short xl[48][128];
    __shared__ float red2[2][32][33];
    int n0 = blockIdx.x * 32;
    int br = blockIdx.y;
    int b = blockIdx.z;
    int tid = threadIdx.x;
    const float* Xb = (br ? A1 : C0) + (size_t)b * CC * NN;
    const float* meB = meanA + ((size_t)br * BB + b) * CC;
    const float* ivB = invA + ((size_t)br * BB + b) * NN;
    const float* mkB = mask + b * NN;

    for (int e = tid; e < 128 * 12; e += 256) {
        int i = e / 12, t = e - i * 12;
        int gn = n0 + t * 4 - 4;
        float4 v = make_float4(0.f, 0.f, 0.f, 0.f);
        if (gn >= 0 && gn + 3 < NN) {
            v = *reinterpret_cast<const float4*>(&Xb[(size_t)i * NN + gn]);
            float me = meB[i];
            float4 iv = *reinterpret_cast<const float4*>(&ivB[gn]);
            float4 mk = *reinterpret_cast<const float4*>(&mkB[gn]);
            v.x = fmaxf((v.x - me) * mk.x * iv.x, 0.f);
            v.y = fmaxf((v.y - me) * mk.y * iv.y, 0.f);
            v.z = fmaxf((v.z - me) * mk.z * iv.z, 0.f);
            v.w = fmaxf((v.w - me) * mk.w * iv.w, 0.f);
        }
        float vv[4] = {v.x, v.y, v.z, v.w};
#pragma unroll
        for (int j = 0; j < 4; ++j) {
            int row = t * 4 + j;
            int col = i ^ ((row & 7) << 3);
            unsigned short h = f2bf(vv[j]);
            xh[row][col] = h;
            xl[row][col] = f2bf(vv[j] - bf2f(h));
        }
    }
    __syncthreads();

    int wid = tid >> 6, lane = tid & 63;
    int i32 = wid & 1, kh = wid >> 1;
    int r = lane & 15, g = lane >> 4;
    size_t brW = (size_t)br * (CH / 32) * (1152 / 32) * 1024;  // FIX: branch weight offset

    f32x4 acc[2][2] = {};
#pragma unroll 3
    for (int t = 0; t < 18; ++t) {
        int k = t >> 1, s = kh * 2 + (t & 1);
        int q32 = k * 4 + s;
        size_t widx = brW + ((size_t)(i32 * 36 + q32)) * 1024 + lane * 8;
        bf16x8 ah[2], al[2];
        ah[0] = *reinterpret_cast<const bf16x8*>(&Wh[widx]);
        ah[1] = *reinterpret_cast<const bf16x8*>(&Wh[widx + 512]);
        al[0] = *reinterpret_cast<const bf16x8*>(&Wl[widx]);
        al[1] = *reinterpret_cast<const bf16x8*>(&Wl[widx + 512]);
        bf16x8 bh[2], bl[2];
#pragma unroll
        for (int fn = 0; fn < 2; ++fn) {
            int row = fn * 16 + r + k;
            int chs = (s * 32 + g * 8) ^ ((row & 7) << 3);
            bh[fn] = *reinterpret_cast<const bf16x8*>(&xh[row][chs]);
            bl[fn] = *reinterpret_cast<const bf16x8*>(&xl[row][chs]);
        }
#pragma unroll
        for (int fc = 0; fc < 2; ++fc)
#pragma unroll
            for (int fn = 0; fn < 2; ++fn) {
                acc[fc][fn] = __builtin_amdgcn_mfma_f32_16x16x32_bf16(ah[fc], bh[fn], acc[fc][fn], 0, 0, 0);
                acc[fc][fn] = __builtin_amdgcn_mfma_f32_16x16x32_bf16(al[fc], bh[fn], acc[fc][fn], 0, 0, 0);
                acc[fc][fn] = __builtin_amdgcn_mfma_f32_16x16x32_bf16(ah[fc], bl[fn], acc[fc][fn], 0, 0, 0);
            }
    }

    if (kh == 1) {
#pragma unroll
        for (int fc = 0; fc < 2; ++fc)
#pragma unroll
            for (int fn = 0; fn < 2; ++fn)
#pragma unroll
                for (int rr = 0; rr < 4; ++rr)
                    red2[i32][fc * 16 + 4 * g + rr][fn * 16 + r] = acc[fc][fn][rr];
    }
    __syncthreads();
    if (kh == 0) {
        float* Outp = (br ? T1p : T0) + (size_t)b * CH * NN;
#pragma unroll
        for (int fc = 0; fc < 2; ++fc)
#pragma unroll
            for (int fn = 0; fn < 2; ++fn) {
                int n = n0 + fn * 16 + r;
#pragma unroll
                for (int rr = 0; rr < 4; ++rr) {
                    int irow = fc * 16 + 4 * g + rr;
                    float v = acc[fc][fn][rr] + red2[i32][irow][fn * 16 + r];
                    Outp[(size_t)(i32 * 32 + irow) * NN + n] = v;
                }
            }
    }
}

// ---------------- MFMA split-K X@W partials (packed W, bf16 LDS A) ----------------
template <int SKN>
__global__ __launch_bounds__(256) void k_matL_mfma(const float* __restrict__ X,
                                                   const unsigned short* __restrict__ Wpk,
                                                   float* __restrict__ Part, int rows) {
    __shared__ __align__(16) unsigned short Xs[64][36];
    int cb = rows >> 6;
    int n0 = blockIdx.x * 64;
    int sk = blockIdx.y;
    int b = blockIdx.z / cb;
    int c0 = (blockIdx.z % cb) * 64;
    int tid = threadIdx.x;
    int wid = tid >> 6, lane = tid & 63;
    int wc = (wid >> 1) * 32;
    int r = lane & 15, g = lane >> 4;
    const float* Xb = X + (size_t)b * rows * NN;
    int nt32 = blockIdx.x * 2 + (wid & 1);
    const unsigned short* Wb = Wpk + ((size_t)b * 32 + nt32) * 32 * 1024;

    int srow = tid >> 2, scol = (tid & 3) * 8;
    f32x4 acc[2][2] = {};
    int m_beg = sk * (NN / SKN);
    for (int m0 = m_beg; m0 < m_beg + NN / SKN; m0 += 32) {
        {
            const float* sp = &Xb[(size_t)(c0 + srow) * NN + m0 + scol];
            float v[8];
            *reinterpret_cast<float4*>(&v[0]) = *reinterpret_cast<const float4*>(sp);
            *reinterpret_cast<float4*>(&v[4]) = *reinterpret_cast<const float4*>(sp + 4);
            unsigned short h[8];
#pragma unroll
            for (int j = 0; j < 8; ++j) h[j] = f2bf(v[j]);
            *reinterpret_cast<ushort4*>(&Xs[srow][scol]) = *reinterpret_cast<ushort4*>(&h[0]);
            *reinterpret_cast<ushort4*>(&Xs[srow][scol + 4]) = *reinterpret_cast<ushort4*>(&h[4]);
        }
        __syncthreads();
        bf16x8 afr[2];
#pragma unroll
        for (int fc = 0; fc < 2; ++fc) {
            const uint2* p = reinterpret_cast<const uint2*>(&Xs[wc + fc * 16 + r][8 * g]);
            uint2 q0 = p[0], q1 = p[1];
            union { unsigned int u[4]; bf16x8 v; } ua;
            ua.u[0] = q0.x; ua.u[1] = q0.y; ua.u[2] = q1.x; ua.u[3] = q1.y;
            afr[fc] = ua.v;
        }
        size_t wb = (size_t)(m0 >> 5) * 1024 + lane * 8;
        bf16x8 bfr[2];
        bfr[0] = *reinterpret_cast<const bf16x8*>(&Wb[wb]);
        bfr[1] = *reinterpret_cast<const bf16x8*>(&Wb[wb + 512]);
#pragma unroll
        for (int fc = 0; fc < 2; ++fc)
#pragma unroll
            for (int fn = 0; fn < 2; ++fn)
                acc[fc][fn] = __builtin_amdgcn_mfma_f32_16x16x32_bf16(afr[fc], bfr[fn], acc[fc][fn], 0, 0, 0);
        __syncthreads();
    }
    int wn = (wid & 1) * 32;
#pragma unroll
    for (int fc = 0; fc < 2; ++fc)
#pragma unroll
        for (int fn = 0; fn < 2; ++fn) {
            int ncol = n0 + wn + fn * 16 + r;
#pragma unroll
            for (int rr = 0; rr < 4; ++rr) {
                int crow = c0 + wc + fc * 16 + 4 * g + rr;
                Part[(((size_t)b * SKN + sk) * rows + crow) * NN + ncol] = acc[fc][fn][rr];
            }
        }
}

// ---------------- reduce partials + epilogue (block = one (b,c) row) ----------------
template <int SKN, int MODE>
__global__ __launch_bounds__(256) void k_matL_fin(const float* __restrict__ X,
                                                  const float* __restrict__ Part,
                                                  const float* __restrict__ Wsum,
                                                  const float* __restrict__ mask,
                                                  const float* __restrict__ T0,
                                                  float* __restrict__ Out,
                                                  float* __restrict__ meanA, int rows) {
    __shared__ float red[256];
    int c = blockIdx.x, b = blockIdx.y;
    int n = threadIdx.x * 4;
    float4 s = make_float4(0.f, 0.f, 0.f, 0.f);
#pragma unroll
    for (int sk = 0; sk < SKN; ++sk) {
        float4 p = *reinterpret_cast<const float4*>(
            &Part[(((size_t)b * SKN + sk) * rows + c) * NN + n]);
        s.x += p.x; s.y += p.y; s.z += p.z; s.w += p.w;
    }
    float4 xv = *reinterpret_cast<const float4*>(&X[((size_t)b * rows + c) * NN + n]);
    float4 wv = *reinterpret_cast<const float4*>(&Wsum[b * NN + n]);
    float4 mv = *reinterpret_cast<const float4*>(&mask[b * NN + n]);
    float y0 = xv.x * wv.x - s.x, y1 = xv.y * wv.y - s.y;
    float y2 = xv.z * wv.z - s.z, y3 = xv.w * wv.w - s.w;
    if (MODE == 0) {
        float4 res = make_float4(y0 * mv.x, y1 * mv.y, y2 * mv.z, y3 * mv.w);
        *reinterpret_cast<float4*>(&Out[((size_t)b * rows + c) * NN + n]) = res;
        float rs = res.x * mv.x + res.y * mv.y + res.z * mv.z + res.w * mv.w;
        float ms = mv.x + mv.y + mv.z + mv.w;
        rs = blockSum(rs, red);
        ms = blockSum(ms, red);
        if (threadIdx.x == 0) meanA[((size_t)BB + b) * CC + c] = rs / ms;
    } else {
        float4 t0 = *reinterpret_cast<const float4*>(&T0[((size_t)b * rows + c) * NN + n]);
        float4 o = *reinterpret_cast<const float4*>(&Out[((size_t)b * rows + c) * NN + n]);
        float4 res = make_float4(o.x - HSTEP * mv.x * (t0.x + y0),
                                 o.y - HSTEP * mv.y * (t0.y + y1),
                                 o.z - HSTEP * mv.z * (t0.z + y2),
                                 o.w - HSTEP * mv.w * (t0.w + y3));
        *reinterpret_cast<float4*>(&Out[((size_t)b * rows + c) * NN + n]) = res;
    }
}

// ---------------- masked row mean (C0, z=0) ----------------
__global__ __launch_bounds__(256) void k_rowmean(const float* __restrict__ X0,
                                                 const float* __restrict__ mask,
                                                 float* __restrict__ meanA) {
    __shared__ float red[256];
    int c = blockIdx.x, b = blockIdx.y, tid = threadIdx.x;
    const float* src = X0 + ((size_t)b * CC + c) * NN;
    const float* m = mask + b * NN;
    float s = 0.f, sm = 0.f;
    for (int n = tid; n < NN; n += 256) { float mv = m[n]; s += src[n] * mv; sm += mv; }
    float ts = blockSum(s, red);
    float tm = blockSum(sm, red);
    if (tid == 0) meanA[(size_t)b * CC + c] = ts / tm;
}

// ---------------- colnorm inv only ----------------
__global__ __launch_bounds__(256) void k_colnorm_inv(const float* __restrict__ X0,
                                                     const float* __restrict__ X1,
                                                     const float* __restrict__ mask,
                                                     const float* __restrict__ meanA,
                                                     float* __restrict__ invA) {
    __shared__ float red[8][32];
    int tid = threadIdx.x;
    int nl = tid & 31, cg = tid >> 5;
    int n = blockIdx.x * 32 + nl;
    int b = blockIdx.y, z = blockIdx.z;
    const float* X = (z ? X1 : X0) + (size_t)b * CC * NN;
    const float* me = meanA + ((size_t)z * BB + b) * CC;
    float mv = mask[b * NN + n];
    float ss = 0.f;
#pragma unroll
    for (int cc = 0; cc < 16; ++cc) {
        int c = cg * 16 + cc;
        float v = (X[(size_t)c * NN + n] - me[c]) * mv;
        ss += v * v;
    }
    red[cg][nl] = ss;
    __syncthreads();
    if (cg < 4) red[cg][nl] += red[cg + 4][nl];
    __syncthreads();
    if (cg < 2) red[cg][nl] += red[cg + 2][nl];
    __syncthreads();
    if (cg < 1) red[0][nl] += red[1][nl];
    __syncthreads();
    if (cg == 0) invA[((size_t)z * BB + b) * NN + n] = rsqrtf(red[0][nl] + 0.001f);
}

// ---------------- close ----------------
__global__ __launch_bounds__(256) void k_close(const float* __restrict__ Zcur,
                                               const float* __restrict__ Kcl,
                                               const float* __restrict__ mask,
                                               float* __restrict__ Zout) {
    __shared__ float red[4][64][COUT];
    int tid = threadIdx.x;
    int nl = tid & 63, cg = tid >> 6;
    int n = blockIdx.x * 64 + nl;
    int b = blockIdx.y;
    float acc[COUT] = {};
#pragma unroll
    for (int cc = 0; cc < 16; ++cc) {
        int c = cg * 16 + cc;
        float zv = Zcur[((size_t)b * CH + c) * NN + n];
#pragma unroll
        for (int o = 0; o < COUT; ++o) acc[o] += Kcl[o * CH + c] * zv;
    }
#pragma unroll
    for (int o = 0; o < COUT; ++o) red[cg][nl][o] = acc[o];
    __syncthreads();
    if (cg == 0) {
        float mv = mask[b * NN + n];
#pragma unroll
        for (int o = 0; o < COUT; ++o) {
            float s = red[0][nl][o] + red[1][nl][o] + red[2][nl][o] + red[3][nl][o];
            Zout[((size_t)b * COUT + o) * NN + n] = s * mv;
        }
    }
}

// ---------------- center3 ----------------
__global__ __launch_bounds__(256) void k_center3(const float* __restrict__ Zout, float* __restrict__ Zc3) {
    __shared__ float red[256];
    int c = blockIdx.x, b = blockIdx.y, tid = threadIdx.x;
    const float* src = Zout + ((size_t)b * COUT + c) * NN;
    float s = 0.f;
    for (int n = tid; n < NN; n += 256) s += src[n];
    float mean = blockSum(s, red) / (float)NN;
    float* dst = Zc3 + ((size_t)b * COUT + c) * NN;
    for (int n = tid; n < NN; n += 256) dst[n] = src[n] - mean;
}

__global__ __launch_bounds__(256) void k_n23(const float* __restrict__ Zc3, float* __restrict__ n23) {
    int n = blockIdx.x * 256 + threadIdx.x;
    int g = blockIdx.y, b = blockIdx.z;
    float s = 0.f;
#pragma unroll
    for (int c = 0; c < 3; ++c) { float v = Zc3[((size_t)b * COUT + g * 3 + c) * NN + n]; s += v * v; }
    n23[((size_t)b * 3 + g) * NN + n] = s;
}

// ---------------- final pairwise distances ----------------
__global__ __launch_bounds__(256) void k_dist(const float* __restrict__ Zc3,
                                              const float* __restrict__ n23,
                                              float* __restrict__ dout) {
    __shared__ float Ai[3][64], Aj[3][64], ni[64], nj[64];
    int bg = blockIdx.z;
    int b = bg / 3, g = bg - 3 * b;
    int i0 = blockIdx.x * 64, j0 = blockIdx.y * 64;
    int tid = threadIdx.x;
    if (tid < 64) ni[tid] = n23[((size_t)b * 3 + g) * NN + i0 + tid];
    else if (tid < 128) { int t = tid - 64; nj[t] = n23[((size_t)b * 3 + g) * NN + j0 + t]; }
    for (int e = tid; e < 192; e += 256) {
        int c = e / 64, t = e - c * 64;
        Ai[c][t] = Zc3[((size_t)b * COUT + g * 3 + c) * NN + i0 + t];
    }
    for (int e = tid; e < 192; e += 256) {
        int c = e / 64, t = e - c * 64;
        Aj[c][t] = Zc3[((size_t)b * COUT + g * 3 + c) * NN + j0 + t];
    }
    __syncthreads();
    int tx = tid & 15, ty = tid >> 4;
    for (int q = 0; q < 4; ++q) {
        int i = ty * 4 + q;
        float a0 = Ai[0][i], a1 = Ai[1][i], a2 = Ai[2][i], n2i = ni[i];
        float res[4];
#pragma unroll
        for (int r = 0; r < 4; ++r) {
            int j = tx * 4 + r;
            float D = n2i + nj[j] - 2.f * (a0 * Aj[0][j] + a1 * Aj[1][j] + a2 * Aj[2][j]);
            D = fmaxf(D, 0.f);
            res[r] = (D > 0.f) ? sqrtf(D) : 0.f;
        }
        *reinterpret_cast<float4*>(&dout[(((size_t)b * 3 + g) * NN + i0 + i) * NN + j0 + tx * 4]) =
            *reinterpret_cast<float4*>(res);
    }
}

// ---------------- driver ----------------
extern "C" void kernel_launch(void* const* d_in, const int* in_sizes, int n_in,
                              void* d_out, int out_size, void* d_ws, size_t ws_size,
                              hipStream_t stream) {
    (void)in_sizes; (void)n_in; (void)out_size; (void)ws_size;
    const float* Zin  = (const float*)d_in[0];
    const float* mask = (const float*)d_in[1];
    const float* Kop  = (const float*)d_in[2];
    const float* Kcl  = (const float*)d_in[3];
    const float* Win  = (const float*)d_in[4];
    const float* Bias = (const float*)d_in[5];
    float* out = (float*)d_out;
    float* ws = (float*)d_ws;

    size_t off = 0;
    float* Zcur = ws + off;  off += (size_t)BB * CH * NN;
    float* C0   = ws + off;  off += (size_t)BB * CC * NN;
    float* C1   = ws + off;  off += (size_t)BB * CC * NN;
    float* A1   = ws + off;  off += (size_t)BB * CC * NN;
    float* T0   = ws + off;  off += (size_t)BB * CH * NN;
    float* T1p  = ws + off;  off += (size_t)BB * CH * NN;
    float* Za   = ws + off;  off += (size_t)BB * 65 * NN;
    float* n2g  = ws + off;  off += (size_t)BB * NN;
    float* Wg   = ws + off;  off += (size_t)BB * NN * NN;
    float* Wsum = ws + off;  off += (size_t)BB * NN;
    float* meanA= ws + off;  off += (size_t)2 * BB * CC;
    float* bks  = ws + off;  off += (size_t)NL * 2 * CC * KS;
    float* Zc3  = ws + off;  off += (size_t)BB * COUT * NN;
    float* n23  = ws + off;  off += (size_t)BB * 3 * NN;
    float* Wsp  = ws + off;  off += (size_t)BB * 16 * NN;
    float* invA = ws + off;  off += (size_t)2 * BB * NN;

    // Scratch in the (as-yet-unwritten) dists region of d_out (25,165,824 floats):
    float* Part = out;                                                   // [0 .. 2,097,152)
    unsigned short* Wpk2  = (unsigned short*)(out + (size_t)4194304);    // matL packed W -> ends 8,388,608
    // packed conv weights (each 1,474,560 shorts = 737,280 float-slots):
    unsigned short* PKc_h = (unsigned short*)(out + (size_t)14680064);
    unsigned short* PKc_l = (unsigned short*)(out + (size_t)15417344);
    unsigned short* PKt_h = (unsigned short*)(out + (size_t)16154624);
    unsigned short* PKt_l = (unsigned short*)(out + (size_t)16891904);   // ends 17,629,184

    const int wtot = NL * 2 * CC * CH * KS;
    k_prep_wbf<<<dim3((wtot + 255) / 256), 256, 0, stream>>>(Win, PKc_h, PKc_l, PKt_h, PKt_l);
    k_prep_bks<<<dim3((NL * 2 * CC * KS + 255) / 256), 256, 0, stream>>>(Win, Bias, bks);
    k_open<<<dim3(NN / 256, CH, BB), 256, 0, stream>>>(Zin, mask, Kop, Zcur);
    k_za<<<dim3(65, BB), 256, 0, stream>>>(Zcur, mask, Za);
    k_n2g<<<dim3(NN / 256, BB), 256, 0, stream>>>(Za, n2g);
    k_gramW<<<dim3(16, 16, BB), 256, 0, stream>>>(Za, n2g, mask, Wg);
    k_wsum_part<<<dim3(NN / 256, 16, BB), 256, 0, stream>>>(Wg, Wsp);
    k_wsum_fin<<<dim3(NN / 256, BB), 256, 0, stream>>>(Wsp, Wsum);
    k_wpack2<<<dim3((int)((size_t)BB * NN * NN / 8 / 256)), 256, 0, stream>>>(Wg, Wpk2);

    for (int l = 0; l < NL; ++l) {
        const unsigned short* PKc_h_l = PKc_h + (size_t)l * 2 * CC * 576;
        const unsigned short* PKc_l_l = PKc_l + (size_t)l * 2 * CC * 576;
        const unsigned short* PKt_h_l = PKt_h + (size_t)l * 2 * CH * 1152;
        const unsigned short* PKt_l_l = PKt_l + (size_t)l * 2 * CH * 1152;
        const float* bksl = bks + (size_t)l * 2 * CC * KS;

        k_conv1_mfma<<<dim3(NN / 64, 4, BB), 256, 0, stream>>>(
            Zcur, PKc_h_l, PKc_l_l, bksl, mask, C0, C1);
        k_matL_mfma<SKC><<<dim3(NN / 64, SKC, BB * (CC / 64)), 256, 0, stream>>>(C1, Wpk2, Part, CC);
        k_matL_fin<SKC, 0><<<dim3(CC, BB), 256, 0, stream>>>(
            C1, Part, Wsum, mask, nullptr, A1, meanA, CC);
        k_rowmean<<<dim3(CC, BB), 256, 0, stream>>>(C0, mask, meanA);
        k_colnorm_inv<<<dim3(NN / 32, BB, 2), 256, 0, stream>>>(C0, A1, mask, meanA, invA);
        k_convT_mfma<<<dim3(NN / 32, 2, BB), 256, 0, stream>>>(
            C0, A1, PKt_h_l, PKt_l_l, mask, meanA, invA, T0, T1p);
        k_matL_mfma<SKH><<<dim3(NN / 64, SKH, BB * (CH / 64)), 256, 0, stream>>>(T1p, Wpk2, Part, CH);
        k_matL_fin<SKH, 1><<<dim3(CH, BB), 256, 0, stream>>>(
            T1p, Part, Wsum, mask, T0, Zcur, nullptr, CH);
    }

    float* Zout = out + (size_t)BB * 3 * NN * NN;
    k_close<<<dim3(NN / 64, BB), 256, 0, stream>>>(Zcur, Kcl, mask, Zout);
    k_center3<<<dim3(COUT, BB), 256, 0, stream>>>(Zout, Zc3);
    k_n23<<<dim3(NN / 256, 3, BB), 256, 0, stream>>>(Zc3, n23);
    k_dist<<<dim3(16, 16, 3 * BB), 256, 0, stream>>>(Zc3, n23, out);
}

// Round 12
// 869.108 us; speedup vs baseline: 1.1791x; 1.0956x over previous
//
#include <hip/hip_runtime.h>
#include <cstddef>

#define BB 8
#define NN 1024
#define CIN 40
#define CH 64
#define CC 128
#define COUT 9
#define KS 9
#define NL 10
#define HSTEP 0.1f
#define SKC 2   // split-K for CC matL
#define SKH 4   // split-K for CH matL

typedef __attribute__((ext_vector_type(8))) short bf16x8;
typedef __attribute__((ext_vector_type(4))) float f32x4;

__device__ __forceinline__ unsigned short f2bf(float f) {
    union { float f; unsigned u; } v;
    v.f = f;
    unsigned u = v.u;
    u += 0x7FFFu + ((u >> 16) & 1u);
    return (unsigned short)(u >> 16);
}
__device__ __forceinline__ float bf2f(unsigned short h) {
    union { unsigned u; float f; } v;
    v.u = ((unsigned)h) << 16;
    return v.f;
}

// packed-fragment address (chunk = 64 lanes x 8 shorts = 512 shorts):
// chunk=((lb*(R/32)+row>>5)*(KDv/32)+col>>5)*2+((row>>4)&1), lane=((col>>3)&3)*16+(row&15)
__device__ __forceinline__ size_t pk_addr(int lb, int row, int col, int R, int KDv) {
    int chunk = ((lb * (R / 32) + (row >> 5)) * (KDv / 32) + (col >> 5)) * 2 + ((row >> 4) & 1);
    int lane = ((col >> 3) & 3) * 16 + (row & 15);
    return ((size_t)chunk * 64 + lane) * 8 + (col & 7);
}

// ---------------- helpers ----------------
__device__ __forceinline__ float blockSum(float v, float* red) {
    int tid = threadIdx.x;
    red[tid] = v;
    __syncthreads();
    for (int s = 128; s > 0; s >>= 1) {
        if (tid < s) red[tid] += red[tid + s];
        __syncthreads();
    }
    float r = red[0];
    __syncthreads();
    return r;
}

__global__ __launch_bounds__(256) void k_zero(float* __restrict__ p, int n) {
    int i = blockIdx.x * 256 + threadIdx.x;
    if (i < n) p[i] = 0.f;
}

// ---------------- conv weights -> packed fragments, k-major contraction, hi/lo ----------------
// conv1 : row=o, col=k*64+i,           R=CC, KDv=576
// conv1T: row=i, col=(8-k)*128+o,      R=CH, KDv=1152
__global__ __launch_bounds__(256) void k_prep_wbf(const float* __restrict__ Win,
                                                  unsigned short* __restrict__ PKc_h,
                                                  unsigned short* __restrict__ PKc_l,
                                                  unsigned short* __restrict__ PKt_h,
                                                  unsigned short* __restrict__ PKt_l) {
    int idx = blockIdx.x * 256 + threadIdx.x;
    const int total = NL * 2 * CC * CH * KS;
    if (idx >= total) return;
    int k = idx % KS;
    int t = idx / KS;
    int i = t % CH;  t /= CH;
    int o = t % CC;  t /= CC;
    int lb = t;
    float v = Win[idx];
    unsigned short h = f2bf(v);
    unsigned short l = f2bf(v - bf2f(h));
    size_t ac = pk_addr(lb, o, k * 64 + i, CC, 576);
    size_t at = pk_addr(lb, i, (8 - k) * 128 + o, CH, 1152);
    PKc_h[ac] = h;
    PKc_l[ac] = l;
    PKt_h[at] = h;
    PKt_l[at] = l;
}

// bks[lb][o][k] = sum_i Win[lb][o][i][k] * Bias[lb][i]
__global__ __launch_bounds__(256) void k_prep_bks(const float* __restrict__ Win,
                                                  const float* __restrict__ Bias,
                                                  float* __restrict__ bks) {
    int idx = blockIdx.x * 256 + threadIdx.x;
    const int total = NL * 2 * CC * KS;
    if (idx >= total) return;
    int k = idx % KS;
    int t = idx / KS;
    int o = t % CC;
    int lb = t / CC;
    float s = 0.f;
    for (int i = 0; i < CH; ++i)
        s += Win[(((size_t)lb * CC + o) * CH + i) * KS + k] * Bias[lb * CH + i];
    bks[idx] = s;
}

// ---------------- open ----------------
__global__ __launch_bounds__(256) void k_open(const float* __restrict__ Zin,
                                              const float* __restrict__ mask,
                                              const float* __restrict__ Kop,
                                              float* __restrict__ Zcur) {
    int n = blockIdx.x * 256 + threadIdx.x;
    int c = blockIdx.y, b = blockIdx.z;
    float acc = 0.f;
    for (int i = 0; i < CIN; ++i)
        acc += Kop[c * CIN + i] * Zin[((size_t)b * CIN + i) * NN + n];
    Zcur[((size_t)b * CH + c) * NN + n] = acc * mask[b * NN + n];
}

// ---------------- Za ----------------
__global__ __launch_bounds__(256) void k_za(const float* __restrict__ Zcur,
                                            const float* __restrict__ mask,
                                            float* __restrict__ Za) {
    __shared__ float red[256];
    int c = blockIdx.x;  // 0..64
    int b = blockIdx.y;
    int tid = threadIdx.x;
    const float* m = mask + b * NN;
    float x[4], mv[4];
    if (c < CH) {
        const float* src = Zcur + ((size_t)b * CH + c) * NN;
#pragma unroll
        for (int j = 0; j < 4; ++j) { int n = tid * 4 + j; x[j] = src[n]; mv[j] = m[n]; }
    } else {
#pragma unroll
        for (int j = 0; j < 4; ++j) { int n = tid * 4 + j; mv[j] = m[n]; x[j] = 0.5f * ((float)n / 1023.f) * mv[j]; }
    }
    float sm = 0.f, sxm = 0.f;
#pragma unroll
    for (int j = 0; j < 4; ++j) { sm += mv[j]; sxm += x[j] * mv[j]; }
    float msum = blockSum(sm, red);
    float xm = blockSum(sxm, red);
    if (c < CH) {
        float mean = xm / msum;
        float ss = 0.f;
#pragma unroll
        for (int j = 0; j < 4; ++j) { x[j] -= mean * mv[j]; ss += x[j] * x[j]; }
        ss = blockSum(ss, red);
        float sc = rsqrtf(ss / msum + 1e-4f);
#pragma unroll
        for (int j = 0; j < 4; ++j) x[j] *= sc;
    }
    float ps = 0.f;
#pragma unroll
    for (int j = 0; j < 4; ++j) ps += x[j];
    float pm = blockSum(ps, red) / (float)NN;
    float* dst = Za + ((size_t)b * 65 + c) * NN;
#pragma unroll
    for (int j = 0; j < 4; ++j) dst[tid * 4 + j] = x[j] - pm;
}

// ---------------- n2 ----------------
__global__ __launch_bounds__(256) void k_n2g(const float* __restrict__ Za, float* __restrict__ n2g) {
    int n = blockIdx.x * 256 + threadIdx.x;
    int b = blockIdx.y;
    float s = 0.f;
    for (int c = 0; c < 65; ++c) { float v = Za[((size_t)b * 65 + c) * NN + n]; s += v * v; }
    n2g[b * NN + n] = s;
}

// ---------------- Gram + W: writes packed bf16 W + atomic fp32 Wsum ----------------
__global__ __launch_bounds__(256) void k_gramW(const float* __restrict__ Za,
                                               const float* __restrict__ n2g,
                                               const float* __restrict__ mask,
                                               unsigned short* __restrict__ Wpk,
                                               float* __restrict__ Wsum) {
    __shared__ float As[65][64];
    __shared__ float Bs2[65][64];
    __shared__ unsigned short wt[64][72];
    __shared__ float csred[16][64];
    int i0 = blockIdx.x * 64, j0 = blockIdx.y * 64, b = blockIdx.z;
    int tid = threadIdx.x;
    for (int e = tid; e < 65 * 64; e += 256) {
        int c = e >> 6, t = e & 63;
        const float* src = Za + ((size_t)b * 65 + c) * NN;
        As[c][t] = src[i0 + t];
        Bs2[c][t] = src[j0 + t];
    }
    __syncthreads();
    int tx = tid & 15, ty = tid >> 4;
    float acc[4][4] = {};
    for (int c = 0; c < 65; ++c) {
        float a[4];
#pragma unroll
        for (int q = 0; q < 4; ++q) a[q] = As[c][ty * 4 + q];
        float bv[4];
        *reinterpret_cast<float4*>(bv) = *reinterpret_cast<const float4*>(&Bs2[c][tx * 4]);
#pragma unroll
        for (int q = 0; q < 4; ++q)
#pragma unroll
            for (int r = 0; r < 4; ++r) acc[q][r] += a[q] * bv[r];
    }
    const float* m = mask + b * NN;
    float csacc[4] = {0.f, 0.f, 0.f, 0.f};
    for (int q = 0; q < 4; ++q) {
        int i = i0 + ty * 4 + q;
        float n2i = n2g[b * NN + i], mi = m[i];
#pragma unroll
        for (int r = 0; r < 4; ++r) {
            int j = j0 + tx * 4 + r;
            float D = n2i + n2g[b * NN + j] - 2.f * acc[q][r];
            D *= (3.f / 65.f);
            D = fmaxf(D, 0.f);
            float dist = (D > 0.f) ? sqrtf(D) : 0.f;
            float mmv = mi * m[j];
            float res = expf(-dist * mmv) * mmv;
            wt[ty * 4 + q][tx * 4 + r] = f2bf(res);
            csacc[r] += res;
        }
    }
#pragma unroll
    for (int r = 0; r < 4; ++r) csred[ty][tx * 4 + r] = csacc[r];
    __syncthreads();
    for (int s = 8; s > 0; s >>= 1) {
        if (ty < s) {
#pragma unroll
            for (int r = 0; r < 4; ++r) csred[ty][tx * 4 + r] += csred[ty + s][tx * 4 + r];
        }
        __syncthreads();
    }
    if (ty == 0) {
#pragma unroll
        for (int r = 0; r < 4; ++r)
            atomicAdd(&Wsum[b * NN + j0 + tx * 4 + r], csred[0][tx * 4 + r]);
    }
    // coalesced packed write
    for (int e = tid; e < 512; e += 256) {
        int li = e >> 3, ljb = (e & 7) * 8;
        int row = i0 + li, col = j0 + ljb;
        int chunk = ((b * 32 + (row >> 5)) * 32 + (col >> 5)) * 2 + ((row >> 4) & 1);
        int lane2 = ((col >> 3) & 3) * 16 + (row & 15);
        unsigned short* dp = Wpk + ((size_t)chunk * 64 + lane2) * 8;
        *reinterpret_cast<ushort4*>(dp) = *reinterpret_cast<ushort4*>(&wt[li][ljb]);
        *reinterpret_cast<ushort4*>(dp + 4) = *reinterpret_cast<ushort4*>(&wt[li][ljb + 4]);
    }
}

// ---------------- conv1 (k-major MFMA): block 64o x 64n, y=(br,o_half) ----------------
// br==1 additionally writes C1 in packed bf16 fragment order (for LDS-free matL).
__global__ __launch_bounds__(256) void k_conv1_mfma(const float* __restrict__ Zcur,
                                                    const unsigned short* __restrict__ Wh,
                                                    const unsigned short* __restrict__ Wl,
                                                    const float* __restrict__ bksl,
                                                    const float* __restrict__ mask,
                                                    float* __restrict__ C0,
                                                    float* __restrict__ C1,
                                                    unsigned short* __restrict__ C1pk) {
    __shared__ __align__(16) unsigned short xh[80][64];
    __shared__ __align__(16) unsigned short xl[80][64];
    int n0 = blockIdx.x * 64;
    int y = blockIdx.y;
    int b = blockIdx.z;
    int br = y >> 1, half = y & 1;
    int tid = threadIdx.x;
    const float* Xb = Zcur + (size_t)b * CH * NN;

    for (int e = tid; e < 64 * 20; e += 256) {
        int i = e / 20, t = e - i * 20;
        int gn = n0 + t * 4 - 4;
        float4 v = make_float4(0.f, 0.f, 0.f, 0.f);
        if (gn >= 0 && gn + 3 < NN) v = *reinterpret_cast<const float4*>(&Xb[(size_t)i * NN + gn]);
        float vv[4] = {v.x, v.y, v.z, v.w};
#pragma unroll
        for (int j = 0; j < 4; ++j) {
            int row = t * 4 + j;
            int col = i ^ ((row & 7) << 3);
            unsigned short h = f2bf(vv[j]);
            xh[row][col] = h;
            xl[row][col] = f2bf(vv[j] - bf2f(h));
        }
    }
    __syncthreads();

    int wid = tid >> 6, lane = tid & 63;
    int wo = (wid >> 1) * 32, wn = (wid & 1) * 32;
    int r = lane & 15, g = lane >> 4;
    int r32 = half * 2 + (wid >> 1);
    size_t brOff = (size_t)br * (CC / 32) * (576 / 32) * 1024;

    f32x4 acc[2][2] = {};
#pragma unroll 3
    for (int q = 0; q < 18; ++q) {
        int k = q >> 1, s = q & 1;
        size_t widx = brOff + ((size_t)(r32 * 18 + q)) * 1024 + lane * 8;
        bf16x8 ah[2], al[2];
        ah[0] = *reinterpret_cast<const bf16x8*>(&Wh[widx]);
        ah[1] = *reinterpret_cast<const bf16x8*>(&Wh[widx + 512]);
        al[0] = *reinterpret_cast<const bf16x8*>(&Wl[widx]);
        al[1] = *reinterpret_cast<const bf16x8*>(&Wl[widx + 512]);
        bf16x8 bh[2], bl[2];
#pragma unroll
        for (int fn = 0; fn < 2; ++fn) {
            int row = wn + fn * 16 + r + k;
            int chs = (s * 32 + g * 8) ^ ((row & 7) << 3);
            bh[fn] = *reinterpret_cast<const bf16x8*>(&xh[row][chs]);
            bl[fn] = *reinterpret_cast<const bf16x8*>(&xl[row][chs]);
        }
#pragma unroll
        for (int fc = 0; fc < 2; ++fc)
#pragma unroll
            for (int fn = 0; fn < 2; ++fn) {
                acc[fc][fn] = __builtin_amdgcn_mfma_f32_16x16x32_bf16(ah[fc], bh[fn], acc[fc][fn], 0, 0, 0);
                acc[fc][fn] = __builtin_amdgcn_mfma_f32_16x16x32_bf16(al[fc], bh[fn], acc[fc][fn], 0, 0, 0);
                acc[fc][fn] = __builtin_amdgcn_mfma_f32_16x16x32_bf16(ah[fc], bl[fn], acc[fc][fn], 0, 0, 0);
            }
    }

    const float* mkB = mask + b * NN;
    float* Outp = (br ? C1 : C0) + ((size_t)b * CC + half * 64) * NN;
    const float* bo_base = bksl + (br * CC + half * 64) * KS;
#pragma unroll
    for (int fc = 0; fc < 2; ++fc) {
#pragma unroll
        for (int fn = 0; fn < 2; ++fn) {
            int n = n0 + wn + fn * 16 + r;
#pragma unroll
            for (int rr = 0; rr < 4; ++rr) {
                int oo = wo + fc * 16 + 4 * g + rr;
                float v = acc[fc][fn][rr];
                const float* bo = bo_base + oo * KS;
                float bias = 0.f;
#pragma unroll
                for (int k = 0; k < KS; ++k) {
                    int nn2 = n + k - 4;
                    if (nn2 >= 0 && nn2 < NN) bias += bo[k];
                }
                v += bias;
                if (br == 0) v *= mkB[n];
                Outp[(size_t)oo * NN + n] = v;
                if (br == 1) {
                    int cg = half * 64 + oo;
                    int chunk = ((b * 4 + (cg >> 5)) * 32 + (n >> 5)) * 2 + ((cg >> 4) & 1);
                    int lane2 = ((n >> 3) & 3) * 16 + (cg & 15);
                    C1pk[((size_t)chunk * 64 + lane2) * 8 + (n & 7)] = f2bf(v);
                }
            }
        }
    }
}

// ---------------- conv1T (k-major MFMA): block 64i x 32n, y=br; in-block split-K ----------------
// br==1 additionally writes T1p packed bf16.
__global__ __launch_bounds__(256) void k_convT_mfma(const float* __restrict__ C0,
                                                    const float* __restrict__ A1,
                                                    const unsigned short* __restrict__ Wh,
                                                    const unsigned short* __restrict__ Wl,
                                                    const float* __restrict__ mask,
                                                    const float* __restrict__ meanA,
                                                    const float* __restrict__ invA,
                                                    float* __restrict__ T0,
                                                    float* __restrict__ T1p,
                                                    unsigned short* __restrict__ T1pk) {
    __shared__ __align__(16) unsigned short xh[48][128];
    __shared__ __align__(16) unsigned short xl[48][128];
    __shared__ float red2[2][32][33];
    int n0 = blockIdx.x * 32;
    int br = blockIdx.y;
    int b = blockIdx.z;
    int tid = threadIdx.x;
    const float* Xb = (br ? A1 : C0) + (size_t)b * CC * NN;
    const float* meB = meanA + ((size_t)br * BB + b) * CC;
    const float* ivB = invA + ((size_t)br * BB + b) * NN;
    const float* mkB = mask + b * NN;

    for (int e = tid; e < 128 * 12; e += 256) {
        int i = e / 12, t = e - i * 12;
        int gn = n0 + t * 4 - 4;
        float4 v = make_float4(0.f, 0.f, 0.f, 0.f);
        if (gn >= 0 && gn + 3 < NN) {
            v = *reinterpret_cast<const float4*>(&Xb[(size_t)i * NN + gn]);
            float me = meB[i];
            float4 iv = *reinterpret_cast<const float4*>(&ivB[gn]);
            float4 mk = *reinterpret_cast<const float4*>(&mkB[gn]);
            v.x = fmaxf((v.x - me) * mk.x * iv.x, 0.f);
            v.y = fmaxf((v.y - me) * mk.y * iv.y, 0.f);
            v.z = fmaxf((v.z - me) * mk.z * iv.z, 0.f);
            v.w = fmaxf((v.w - me) * mk.w * iv.w, 0.f);
        }
        float vv[4] = {v.x, v.y, v.z, v.w};
#pragma unroll
        for (int j = 0; j < 4; ++j) {
            int row = t * 4 + j;
            int col = i ^ ((row & 7) << 3);
            unsigned short h = f2bf(vv[j]);
            xh[row][col] = h;
            xl[row][col] = f2bf(vv[j] - bf2f(h));
        }
    }
    __syncthreads();

    int wid = tid >> 6, lane = tid & 63;
    int i32 = wid & 1, kh = wid >> 1;
    int r = lane & 15, g = lane >> 4;
    size_t brW = (size_t)br * (CH / 32) * (1152 / 32) * 1024;

    f32x4 acc[2][2] = {};
#pragma unroll 3
    for (int t = 0; t < 18; ++t) {
        int k = t >> 1, s = kh * 2 + (t & 1);
        int q32 = k * 4 + s;
        size_t widx = brW + ((size_t)(i32 * 36 + q32)) * 1024 + lane * 8;
        bf16x8 ah[2], al[2];
        ah[0] = *reinterpret_cast<const bf16x8*>(&Wh[widx]);
        ah[1] = *reinterpret_cast<const bf16x8*>(&Wh[widx + 512]);
        al[0] = *reinterpret_cast<const bf16x8*>(&Wl[widx]);
        al[1] = *reinterpret_cast<const bf16x8*>(&Wl[widx + 512]);
        bf16x8 bh[2], bl[2];
#pragma unroll
        for (int fn = 0; fn < 2; ++fn) {
            int row = fn * 16 + r + k;
            int chs = (s * 32 + g * 8) ^ ((row & 7) << 3);
            bh[fn] = *reinterpret_cast<const bf16x8*>(&xh[row][chs]);
            bl[fn] = *reinterpret_cast<const bf16x8*>(&xl[row][chs]);
        }
#pragma unroll
        for (int fc = 0; fc < 2; ++fc)
#pragma unroll
            for (int fn = 0; fn < 2; ++fn) {
                acc[fc][fn] = __builtin_amdgcn_mfma_f32_16x16x32_bf16(ah[fc], bh[fn], acc[fc][fn], 0, 0, 0);
                acc[fc][fn] = __builtin_amdgcn_mfma_f32_16x16x32_bf16(al[fc], bh[fn], acc[fc][fn], 0, 0, 0);
                acc[fc][fn] = __builtin_amdgcn_mfma_f32_16x16x32_bf16(ah[fc], bl[fn], acc[fc][fn], 0, 0, 0);
            }
    }

    if (kh == 1) {
#pragma unroll
        for (int fc = 0; fc < 2; ++fc)
#pragma unroll
            for (int fn = 0; fn < 2; ++fn)
#pragma unroll
                for (int rr = 0; rr < 4; ++rr)
                    red2[i32][fc * 16 + 4 * g + rr][fn * 16 + r] = acc[fc][fn][rr];
    }
    __syncthreads();
    if (kh == 0) {
        float* Outp = (br ? T1p : T0) + (size_t)b * CH * NN;
#pragma unroll
        for (int fc = 0; fc < 2; ++fc)
#pragma unroll
            for (int fn = 0; fn < 2; ++fn) {
                int n = n0 + fn * 16 + r;
#pragma unroll
                for (int rr = 0; rr < 4; ++rr) {
                    int irow = fc * 16 + 4 * g + rr;
                    float v = acc[fc][fn][rr] + red2[i32][irow][fn * 16 + r];
                    Outp[(size_t)(i32 * 32 + irow) * NN + n] = v;
                    if (br == 1) {
                        int cg = i32 * 32 + irow;
                        int chunk = ((b * 2 + (cg >> 5)) * 32 + (n >> 5)) * 2 + ((cg >> 4) & 1);
                        int lane2 = ((n >> 3) & 3) * 16 + (cg & 15);
                        T1pk[((size_t)chunk * 64 + lane2) * 8 + (n & 7)] = f2bf(v);
                    }
                }
            }
    }
}

// ---------------- LDS-free MFMA split-K X@W partials (packed X, packed W) ----------------
template <int SKN>
__global__ __launch_bounds__(256) void k_matL_mfma(const unsigned short* __restrict__ Xpk,
                                                   const unsigned short* __restrict__ Wpk,
                                                   float* __restrict__ Part, int rows) {
    int cb = rows >> 6;
    int sk = blockIdx.y;
    int b = blockIdx.z / cb;
    int c0 = (blockIdx.z % cb) * 64;
    int tid = threadIdx.x;
    int wid = tid >> 6, lane = tid & 63;
    int wc = (wid >> 1) * 32;
    int r = lane & 15, g = lane >> 4;
    int rowsT = rows >> 5;
    int ct = (c0 >> 5) + (wid >> 1);
    int nt32 = blockIdx.x * 2 + (wid & 1);
    const unsigned short* Xb = Xpk + ((size_t)(b * rowsT + ct)) * 32768 + (size_t)lane * 8;
    const unsigned short* Wb = Wpk + ((size_t)(b * 32 + nt32)) * 32768 + (size_t)lane * 8;

    f32x4 acc[2][2] = {};
    int ms_beg = sk * (32 / SKN);
#pragma unroll 4
    for (int ms = ms_beg; ms < ms_beg + 32 / SKN; ++ms) {
        bf16x8 a0 = *reinterpret_cast<const bf16x8*>(&Xb[(size_t)ms * 1024]);
        bf16x8 a1 = *reinterpret_cast<const bf16x8*>(&Xb[(size_t)ms * 1024 + 512]);
        bf16x8 w0 = *reinterpret_cast<const bf16x8*>(&Wb[(size_t)ms * 1024]);
        bf16x8 w1 = *reinterpret_cast<const bf16x8*>(&Wb[(size_t)ms * 1024 + 512]);
        acc[0][0] = __builtin_amdgcn_mfma_f32_16x16x32_bf16(a0, w0, acc[0][0], 0, 0, 0);
        acc[0][1] = __builtin_amdgcn_mfma_f32_16x16x32_bf16(a0, w1, acc[0][1], 0, 0, 0);
        acc[1][0] = __builtin_amdgcn_mfma_f32_16x16x32_bf16(a1, w0, acc[1][0], 0, 0, 0);
        acc[1][1] = __builtin_amdgcn_mfma_f32_16x16x32_bf16(a1, w1, acc[1][1], 0, 0, 0);
    }
    int n0 = blockIdx.x * 64;
    int wn = (wid & 1) * 32;
#pragma unroll
    for (int fc = 0; fc < 2; ++fc)
#pragma unroll
        for (int fn = 0; fn < 2; ++fn) {
            int ncol = n0 + wn + fn * 16 + r;
#pragma unroll
            for (int rr = 0; rr < 4; ++rr) {
                int crow = c0 + wc + fc * 16 + 4 * g + rr;
                Part[(((size_t)b * SKN + sk) * rows + crow) * NN + ncol] = acc[fc][fn][rr];
            }
        }
}

// ---------------- reduce partials + epilogue (block = one (b,c) row) ----------------
template <int SKN, int MODE>
__global__ __launch_bounds__(256) void k_matL_fin(const float* __restrict__ X,
                                                  const float* __restrict__ Part,
                                                  const float* __restrict__ Wsum,
                                                  const float* __restrict__ mask,
                                                  const float* __restrict__ T0,
                                                  float* __restrict__ Out,
                                                  float* __restrict__ meanA, int rows) {
    __shared__ float red[256];
    int c = blockIdx.x, b = blockIdx.y;
    int n = threadIdx.x * 4;
    float4 s = make_float4(0.f, 0.f, 0.f, 0.f);
#pragma unroll
    for (int sk = 0; sk < SKN; ++sk) {
        float4 p = *reinterpret_cast<const float4*>(
            &Part[(((size_t)b * SKN + sk) * rows + c) * NN + n]);
        s.x += p.x; s.y += p.y; s.z += p.z; s.w += p.w;
    }
    float4 xv = *reinterpret_cast<const float4*>(&X[((size_t)b * rows + c) * NN + n]);
    float4 wv = *reinterpret_cast<const float4*>(&Wsum[b * NN + n]);
    float4 mv = *reinterpret_cast<const float4*>(&mask[b * NN + n]);
    float y0 = xv.x * wv.x - s.x, y1 = xv.y * wv.y - s.y;
    float y2 = xv.z * wv.z - s.z, y3 = xv.w * wv.w - s.w;
    if (MODE == 0) {
        float4 res = make_float4(y0 * mv.x, y1 * mv.y, y2 * mv.z, y3 * mv.w);
        *reinterpret_cast<float4*>(&Out[((size_t)b * rows + c) * NN + n]) = res;
        float rs = res.x * mv.x + res.y * mv.y + res.z * mv.z + res.w * mv.w;
        float ms = mv.x + mv.y + mv.z + mv.w;
        rs = blockSum(rs, red);
        ms = blockSum(ms, red);
        if (threadIdx.x == 0) meanA[((size_t)BB + b) * CC + c] = rs / ms;
    } else {
        float4 t0 = *reinterpret_cast<const float4*>(&T0[((size_t)b * rows + c) * NN + n]);
        float4 o = *reinterpret_cast<const float4*>(&Out[((size_t)b * rows + c) * NN + n]);
        float4 res = make_float4(o.x - HSTEP * mv.x * (t0.x + y0),
                                 o.y - HSTEP * mv.y * (t0.y + y1),
                                 o.z - HSTEP * mv.z * (t0.z + y2),
                                 o.w - HSTEP * mv.w * (t0.w + y3));
        *reinterpret_cast<float4*>(&Out[((size_t)b * rows + c) * NN + n]) = res;
    }
}

// ---------------- masked row mean (C0, z=0) ----------------
__global__ __launch_bounds__(256) void k_rowmean(const float* __restrict__ X0,
                                                 const float* __restrict__ mask,
                                                 float* __restrict__ meanA) {
    __shared__ float red[256];
    int c = blockIdx.x, b = blockIdx.y, tid = threadIdx.x;
    const float* src = X0 + ((size_t)b * CC + c) * NN;
    const float* m = mask + b * NN;
    float s = 0.f, sm = 0.f;
    for (int n = tid; n < NN; n += 256) { float mv = m[n]; s += src[n] * mv; sm += mv; }
    float ts = blockSum(s, red);
    float tm = blockSum(sm, red);
    if (tid == 0) meanA[(size_t)b * CC + c] = ts / tm;
}

// ---------------- colnorm inv only ----------------
__global__ __launch_bounds__(256) void k_colnorm_inv(const float* __restrict__ X0,
                                                     const float* __restrict__ X1,
                                                     const float* __restrict__ mask,
                                                     const float* __restrict__ meanA,
                                                     float* __restrict__ invA) {
    __shared__ float red[8][32];
    int tid = threadIdx.x;
    int nl = tid & 31, cg = tid >> 5;
    int n = blockIdx.x * 32 + nl;
    int b = blockIdx.y, z = blockIdx.z;
    const float* X = (z ? X1 : X0) + (size_t)b * CC * NN;
    const float* me = meanA + ((size_t)z * BB + b) * CC;
    float mv = mask[b * NN + n];
    float ss = 0.f;
#pragma unroll
    for (int cc = 0; cc < 16; ++cc) {
        int c = cg * 16 + cc;
        float v = (X[(size_t)c * NN + n] - me[c]) * mv;
        ss += v * v;
    }
    red[cg][nl] = ss;
    __syncthreads();
    if (cg < 4) red[cg][nl] += red[cg + 4][nl];
    __syncthreads();
    if (cg < 2) red[cg][nl] += red[cg + 2][nl];
    __syncthreads();
    if (cg < 1) red[0][nl] += red[1][nl];
    __syncthreads();
    if (cg == 0) invA[((size_t)z * BB + b) * NN + n] = rsqrtf(red[0][nl] + 0.001f);
}

// ---------------- close ----------------
__global__ __launch_bounds__(256) void k_close(const float* __restrict__ Zcur,
                                               const float* __restrict__ Kcl,
                                               const float* __restrict__ mask,
                                               float* __restrict__ Zout) {
    __shared__ float red[4][64][COUT];
    int tid = threadIdx.x;
    int nl = tid & 63, cg = tid >> 6;
    int n = blockIdx.x * 64 + nl;
    int b = blockIdx.y;
    float acc[COUT] = {};
#pragma unroll
    for (int cc = 0; cc < 16; ++cc) {
        int c = cg * 16 + cc;
        float zv = Zcur[((size_t)b * CH + c) * NN + n];
#pragma unroll
        for (int o = 0; o < COUT; ++o) acc[o] += Kcl[o * CH + c] * zv;
    }
#pragma unroll
    for (int o = 0; o < COUT; ++o) red[cg][nl][o] = acc[o];
    __syncthreads();
    if (cg == 0) {
        float mv = mask[b * NN + n];
#pragma unroll
        for (int o = 0; o < COUT; ++o) {
            float s = red[0][nl][o] + red[1][nl][o] + red[2][nl][o] + red[3][nl][o];
            Zout[((size_t)b * COUT + o) * NN + n] = s * mv;
        }
    }
}

// ---------------- center3 ----------------
__global__ __launch_bounds__(256) void k_center3(const float* __restrict__ Zout, float* __restrict__ Zc3) {
    __shared__ float red[256];
    int c = blockIdx.x, b = blockIdx.y, tid = threadIdx.x;
    const float* src = Zout + ((size_t)b * COUT + c) * NN;
    float s = 0.f;
    for (int n = tid; n < NN; n += 256) s += src[n];
    float mean = blockSum(s, red) / (float)NN;
    float* dst = Zc3 + ((size_t)b * COUT + c) * NN;
    for (int n = tid; n < NN; n += 256) dst[n] = src[n] - mean;
}

__global__ __launch_bounds__(256) void k_n23(const float* __restrict__ Zc3, float* __restrict__ n23) {
    int n = blockIdx.x * 256 + threadIdx.x;
    int g = blockIdx.y, b = blockIdx.z;
    float s = 0.f;
#pragma unroll
    for (int c = 0; c < 3; ++c) { float v = Zc3[((size_t)b * COUT + g * 3 + c) * NN + n]; s += v * v; }
    n23[((size_t)b * 3 + g) * NN + n] = s;
}

// ---------------- final pairwise distances ----------------
__global__ __launch_bounds__(256) void k_dist(const float* __restrict__ Zc3,
                                              const float* __restrict__ n23,
                                              float* __restrict__ dout) {
    __shared__ float Ai[3][64], Aj[3][64], ni[64], nj[64];
    int bg = blockIdx.z;
    int b = bg / 3, g = bg - 3 * b;
    int i0 = blockIdx.x * 64, j0 = blockIdx.y * 64;
    int tid = threadIdx.x;
    if (tid < 64) ni[tid] = n23[((size_t)b * 3 + g) * NN + i0 + tid];
    else if (tid < 128) { int t = tid - 64; nj[t] = n23[((size_t)b * 3 + g) * NN + j0 + t]; }
    for (int e = tid; e < 192; e += 256) {
        int c = e / 64, t = e - c * 64;
        Ai[c][t] = Zc3[((size_t)b * COUT + g * 3 + c) * NN + i0 + t];
    }
    for (int e = tid; e < 192; e += 256) {
        int c = e / 64, t = e - c * 64;
        Aj[c][t] = Zc3[((size_t)b * COUT + g * 3 + c) * NN + j0 + t];
    }
    __syncthreads();
    int tx = tid & 15, ty = tid >> 4;
    for (int q = 0; q < 4; ++q) {
        int i = ty * 4 + q;
        float a0 = Ai[0][i], a1 = Ai[1][i], a2 = Ai[2][i], n2i = ni[i];
        float res[4];
#pragma unroll
        for (int r = 0; r < 4; ++r) {
            int j = tx * 4 + r;
            float D = n2i + nj[j] - 2.f * (a0 * Aj[0][j] + a1 * Aj[1][j] + a2 * Aj[2][j]);
            D = fmaxf(D, 0.f);
            res[r] = (D > 0.f) ? sqrtf(D) : 0.f;
        }
        *reinterpret_cast<float4*>(&dout[(((size_t)b * 3 + g) * NN + i0 + i) * NN + j0 + tx * 4]) =
            *reinterpret_cast<float4*>(res);
    }
}

// ---------------- driver ----------------
extern "C" void kernel_launch(void* const* d_in, const int* in_sizes, int n_in,
                              void* d_out, int out_size, void* d_ws, size_t ws_size,
                              hipStream_t stream) {
    (void)in_sizes; (void)n_in; (void)out_size; (void)ws_size;
    const float* Zin  = (const float*)d_in[0];
    const float* mask = (const float*)d_in[1];
    const float* Kop  = (const float*)d_in[2];
    const float* Kcl  = (const float*)d_in[3];
    const float* Win  = (const float*)d_in[4];
    const float* Bias = (const float*)d_in[5];
    float* out = (float*)d_out;
    float* ws = (float*)d_ws;

    size_t off = 0;
    float* Zcur = ws + off;  off += (size_t)BB * CH * NN;
    float* C0   = ws + off;  off += (size_t)BB * CC * NN;
    float* C1   = ws + off;  off += (size_t)BB * CC * NN;
    float* A1   = ws + off;  off += (size_t)BB * CC * NN;
    float* T0   = ws + off;  off += (size_t)BB * CH * NN;
    float* T1p  = ws + off;  off += (size_t)BB * CH * NN;
    float* Za   = ws + off;  off += (size_t)BB * 65 * NN;
    float* n2g  = ws + off;  off += (size_t)BB * NN;
    float* Wsum = ws + off;  off += (size_t)BB * NN;
    float* meanA= ws + off;  off += (size_t)2 * BB * CC;
    float* bks  = ws + off;  off += (size_t)NL * 2 * CC * KS;
    float* Zc3  = ws + off;  off += (size_t)BB * COUT * NN;
    float* n23  = ws + off;  off += (size_t)BB * 3 * NN;
    float* invA = ws + off;  off += (size_t)2 * BB * NN;

    // Scratch in the (as-yet-unwritten) dists region of d_out (25,165,824 floats):
    float* Part = out;                                                   // [0 .. 2,097,152)
    unsigned short* Wpk2  = (unsigned short*)(out + (size_t)4194304);    // [.. 8,388,608)
    unsigned short* C1pk  = (unsigned short*)(out + (size_t)8388608);    // 1,048,576 shorts
    unsigned short* T1pk  = (unsigned short*)(out + (size_t)8912896);    // 524,288 shorts
    unsigned short* PKc_h = (unsigned short*)(out + (size_t)14680064);
    unsigned short* PKc_l = (unsigned short*)(out + (size_t)15417344);
    unsigned short* PKt_h = (unsigned short*)(out + (size_t)16154624);
    unsigned short* PKt_l = (unsigned short*)(out + (size_t)16891904);   // ends 17,629,184

    const int wtot = NL * 2 * CC * CH * KS;
    k_prep_wbf<<<dim3((wtot + 255) / 256), 256, 0, stream>>>(Win, PKc_h, PKc_l, PKt_h, PKt_l);
    k_prep_bks<<<dim3((NL * 2 * CC * KS + 255) / 256), 256, 0, stream>>>(Win, Bias, bks);
    k_zero<<<dim3(BB * NN / 256), 256, 0, stream>>>(Wsum, BB * NN);
    k_open<<<dim3(NN / 256, CH, BB), 256, 0, stream>>>(Zin, mask, Kop, Zcur);
    k_za<<<dim3(65, BB), 256, 0, stream>>>(Zcur, mask, Za);
    k_n2g<<<dim3(NN / 256, BB), 256, 0, stream>>>(Za, n2g);
    k_gramW<<<dim3(16, 16, BB), 256, 0, stream>>>(Za, n2g, mask, Wpk2, Wsum);

    for (int l = 0; l < NL; ++l) {
        const unsigned short* PKc_h_l = PKc_h + (size_t)l * 2 * CC * 576;
        const unsigned short* PKc_l_l = PKc_l + (size_t)l * 2 * CC * 576;
        const unsigned short* PKt_h_l = PKt_h + (size_t)l * 2 * CH * 1152;
        const unsigned short* PKt_l_l = PKt_l + (size_t)l * 2 * CH * 1152;
        const float* bksl = bks + (size_t)l * 2 * CC * KS;

        k_conv1_mfma<<<dim3(NN / 64, 4, BB), 256, 0, stream>>>(
            Zcur, PKc_h_l, PKc_l_l, bksl, mask, C0, C1, C1pk);
        k_matL_mfma<SKC><<<dim3(NN / 64, SKC, BB * (CC / 64)), 256, 0, stream>>>(C1pk, Wpk2, Part, CC);
        k_matL_fin<SKC, 0><<<dim3(CC, BB), 256, 0, stream>>>(
            C1, Part, Wsum, mask, nullptr, A1, meanA, CC);
        k_rowmean<<<dim3(CC, BB), 256, 0, stream>>>(C0, mask, meanA);
        k_colnorm_inv<<<dim3(NN / 32, BB, 2), 256, 0, stream>>>(C0, A1, mask, meanA, invA);
        k_convT_mfma<<<dim3(NN / 32, 2, BB), 256, 0, stream>>>(
            C0, A1, PKt_h_l, PKt_l_l, mask, meanA, invA, T0, T1p, T1pk);
        k_matL_mfma<SKH><<<dim3(NN / 64, SKH, BB * (CH / 64)), 256, 0, stream>>>(T1pk, Wpk2, Part, CH);
        k_matL_fin<SKH, 1><<<dim3(CH, BB), 256, 0, stream>>>(
            T1p, Part, Wsum, mask, T0, Zcur, nullptr, CH);
    }

    float* Zout = out + (size_t)BB * 3 * NN * NN;
    k_close<<<dim3(NN / 64, BB), 256, 0, stream>>>(Zcur, Kcl, mask, Zout);
    k_center3<<<dim3(COUT, BB), 256, 0, stream>>>(Zout, Zc3);
    k_n23<<<dim3(NN / 256, 3, BB), 256, 0, stream>>>(Zc3, n23);
    k_dist<<<dim3(16, 16, 3 * BB), 256, 0, stream>>>(Zc3, n23, out);
}

// Round 13
// 817.711 us; speedup vs baseline: 1.2533x; 1.0629x over previous
//
#include <hip/hip_runtime.h>
#include <cstddef>

#define BB 8
#define NN 1024
#define CIN 40
#define CH 64
#define CC 128
#define COUT 9
#define KS 9
#define NL 10
#define HSTEP 0.1f
#define SKC 2   // split-K for CC matL
#define SKH 4   // split-K for CH matL

typedef __attribute__((ext_vector_type(8))) short bf16x8;
typedef __attribute__((ext_vector_type(4))) float f32x4;

__device__ __forceinline__ unsigned short f2bf(float f) {
    union { float f; unsigned u; } v;
    v.f = f;
    unsigned u = v.u;
    u += 0x7FFFu + ((u >> 16) & 1u);
    return (unsigned short)(u >> 16);
}
__device__ __forceinline__ float bf2f(unsigned short h) {
    union { unsigned u; float f; } v;
    v.u = ((unsigned)h) << 16;
    return v.f;
}

// packed-fragment address (chunk = 64 lanes x 8 shorts = 512 shorts):
// chunk=((lb*(R/32)+row>>5)*(KDv/32)+col>>5)*2+((row>>4)&1), lane=((col>>3)&3)*16+(row&15)
__device__ __forceinline__ size_t pk_addr(int lb, int row, int col, int R, int KDv) {
    int chunk = ((lb * (R / 32) + (row >> 5)) * (KDv / 32) + (col >> 5)) * 2 + ((row >> 4) & 1);
    int lane = ((col >> 3) & 3) * 16 + (row & 15);
    return ((size_t)chunk * 64 + lane) * 8 + (col & 7);
}

// ---------------- helpers ----------------
__device__ __forceinline__ float blockSum(float v, float* red) {
    int tid = threadIdx.x;
    red[tid] = v;
    __syncthreads();
    for (int s = 128; s > 0; s >>= 1) {
        if (tid < s) red[tid] += red[tid + s];
        __syncthreads();
    }
    float r = red[0];
    __syncthreads();
    return r;
}

__global__ __launch_bounds__(256) void k_zero(float* __restrict__ p, int n) {
    int i = blockIdx.x * 256 + threadIdx.x;
    if (i < n) p[i] = 0.f;
}

// ---------------- conv weights -> packed fragments, k-major contraction, hi/lo ----------------
// conv1 : row=o, col=k*64+i,           R=CC, KDv=576
// conv1T: row=i, col=(8-k)*128+o,      R=CH, KDv=1152
__global__ __launch_bounds__(256) void k_prep_wbf(const float* __restrict__ Win,
                                                  unsigned short* __restrict__ PKc_h,
                                                  unsigned short* __restrict__ PKc_l,
                                                  unsigned short* __restrict__ PKt_h,
                                                  unsigned short* __restrict__ PKt_l) {
    int idx = blockIdx.x * 256 + threadIdx.x;
    const int total = NL * 2 * CC * CH * KS;
    if (idx >= total) return;
    int k = idx % KS;
    int t = idx / KS;
    int i = t % CH;  t /= CH;
    int o = t % CC;  t /= CC;
    int lb = t;
    float v = Win[idx];
    unsigned short h = f2bf(v);
    unsigned short l = f2bf(v - bf2f(h));
    size_t ac = pk_addr(lb, o, k * 64 + i, CC, 576);
    size_t at = pk_addr(lb, i, (8 - k) * 128 + o, CH, 1152);
    PKc_h[ac] = h;
    PKc_l[ac] = l;
    PKt_h[at] = h;
    PKt_l[at] = l;
}

// bks[lb][o][k] = sum_i Win[lb][o][i][k] * Bias[lb][i]
__global__ __launch_bounds__(256) void k_prep_bks(const float* __restrict__ Win,
                                                  const float* __restrict__ Bias,
                                                  float* __restrict__ bks) {
    int idx = blockIdx.x * 256 + threadIdx.x;
    const int total = NL * 2 * CC * KS;
    if (idx >= total) return;
    int k = idx % KS;
    int t = idx / KS;
    int o = t % CC;
    int lb = t / CC;
    float s = 0.f;
    for (int i = 0; i < CH; ++i)
        s += Win[(((size_t)lb * CC + o) * CH + i) * KS + k] * Bias[lb * CH + i];
    bks[idx] = s;
}

// ---------------- open ----------------
__global__ __launch_bounds__(256) void k_open(const float* __restrict__ Zin,
                                              const float* __restrict__ mask,
                                              const float* __restrict__ Kop,
                                              float* __restrict__ Zcur) {
    int n = blockIdx.x * 256 + threadIdx.x;
    int c = blockIdx.y, b = blockIdx.z;
    float acc = 0.f;
    for (int i = 0; i < CIN; ++i)
        acc += Kop[c * CIN + i] * Zin[((size_t)b * CIN + i) * NN + n];
    Zcur[((size_t)b * CH + c) * NN + n] = acc * mask[b * NN + n];
}

// ---------------- Za ----------------
__global__ __launch_bounds__(256) void k_za(const float* __restrict__ Zcur,
                                            const float* __restrict__ mask,
                                            float* __restrict__ Za) {
    __shared__ float red[256];
    int c = blockIdx.x;  // 0..64
    int b = blockIdx.y;
    int tid = threadIdx.x;
    const float* m = mask + b * NN;
    float x[4], mv[4];
    if (c < CH) {
        const float* src = Zcur + ((size_t)b * CH + c) * NN;
#pragma unroll
        for (int j = 0; j < 4; ++j) { int n = tid * 4 + j; x[j] = src[n]; mv[j] = m[n]; }
    } else {
#pragma unroll
        for (int j = 0; j < 4; ++j) { int n = tid * 4 + j; mv[j] = m[n]; x[j] = 0.5f * ((float)n / 1023.f) * mv[j]; }
    }
    float sm = 0.f, sxm = 0.f;
#pragma unroll
    for (int j = 0; j < 4; ++j) { sm += mv[j]; sxm += x[j] * mv[j]; }
    float msum = blockSum(sm, red);
    float xm = blockSum(sxm, red);
    if (c < CH) {
        float mean = xm / msum;
        float ss = 0.f;
#pragma unroll
        for (int j = 0; j < 4; ++j) { x[j] -= mean * mv[j]; ss += x[j] * x[j]; }
        ss = blockSum(ss, red);
        float sc = rsqrtf(ss / msum + 1e-4f);
#pragma unroll
        for (int j = 0; j < 4; ++j) x[j] *= sc;
    }
    float ps = 0.f;
#pragma unroll
    for (int j = 0; j < 4; ++j) ps += x[j];
    float pm = blockSum(ps, red) / (float)NN;
    float* dst = Za + ((size_t)b * 65 + c) * NN;
#pragma unroll
    for (int j = 0; j < 4; ++j) dst[tid * 4 + j] = x[j] - pm;
}

// ---------------- Gram + W: local n2, writes packed bf16 W + atomic fp32 Wsum ----------------
__global__ __launch_bounds__(256) void k_gramW(const float* __restrict__ Za,
                                               const float* __restrict__ mask,
                                               unsigned short* __restrict__ Wpk,
                                               float* __restrict__ Wsum) {
    __shared__ float As[65][68];
    __shared__ float Bs2[65][68];
    __shared__ unsigned short wt[64][72];
    __shared__ float csred[16][64];
    __shared__ float n2is[64], n2js[64];
    int i0 = blockIdx.x * 64, j0 = blockIdx.y * 64, b = blockIdx.z;
    int tid = threadIdx.x;
    for (int e = tid; e < 65 * 64; e += 256) {
        int c = e >> 6, t = e & 63;
        const float* src = Za + ((size_t)b * 65 + c) * NN;
        As[c][t] = src[i0 + t];
        Bs2[c][t] = src[j0 + t];
    }
    __syncthreads();
    if (tid < 64) {
        float s = 0.f;
        for (int c = 0; c < 65; ++c) { float v = As[c][tid]; s += v * v; }
        n2is[tid] = s;
    } else if (tid < 128) {
        int t = tid - 64;
        float s = 0.f;
        for (int c = 0; c < 65; ++c) { float v = Bs2[c][t]; s += v * v; }
        n2js[t] = s;
    }
    __syncthreads();
    int tx = tid & 15, ty = tid >> 4;
    float acc[4][4] = {};
    for (int c = 0; c < 65; ++c) {
        float a[4];
#pragma unroll
        for (int q = 0; q < 4; ++q) a[q] = As[c][ty * 4 + q];
        float bv[4];
        *reinterpret_cast<float4*>(bv) = *reinterpret_cast<const float4*>(&Bs2[c][tx * 4]);
#pragma unroll
        for (int q = 0; q < 4; ++q)
#pragma unroll
            for (int r = 0; r < 4; ++r) acc[q][r] += a[q] * bv[r];
    }
    const float* m = mask + b * NN;
    float csacc[4] = {0.f, 0.f, 0.f, 0.f};
    for (int q = 0; q < 4; ++q) {
        int i = i0 + ty * 4 + q;
        float n2i = n2is[ty * 4 + q], mi = m[i];
#pragma unroll
        for (int r = 0; r < 4; ++r) {
            int j = j0 + tx * 4 + r;
            float D = n2i + n2js[tx * 4 + r] - 2.f * acc[q][r];
            D *= (3.f / 65.f);
            D = fmaxf(D, 0.f);
            float dist = (D > 0.f) ? sqrtf(D) : 0.f;
            float mmv = mi * m[j];
            float res = expf(-dist * mmv) * mmv;
            wt[ty * 4 + q][tx * 4 + r] = f2bf(res);
            csacc[r] += res;
        }
    }
#pragma unroll
    for (int r = 0; r < 4; ++r) csred[ty][tx * 4 + r] = csacc[r];
    __syncthreads();
    for (int s = 8; s > 0; s >>= 1) {
        if (ty < s) {
#pragma unroll
            for (int r = 0; r < 4; ++r) csred[ty][tx * 4 + r] += csred[ty + s][tx * 4 + r];
        }
        __syncthreads();
    }
    if (ty == 0) {
#pragma unroll
        for (int r = 0; r < 4; ++r)
            atomicAdd(&Wsum[b * NN + j0 + tx * 4 + r], csred[0][tx * 4 + r]);
    }
    for (int e = tid; e < 512; e += 256) {
        int li = e >> 3, ljb = (e & 7) * 8;
        int row = i0 + li, col = j0 + ljb;
        int chunk = ((b * 32 + (row >> 5)) * 32 + (col >> 5)) * 2 + ((row >> 4) & 1);
        int lane2 = ((col >> 3) & 3) * 16 + (row & 15);
        unsigned short* dp = Wpk + ((size_t)chunk * 64 + lane2) * 8;
        *reinterpret_cast<ushort4*>(dp) = *reinterpret_cast<ushort4*>(&wt[li][ljb]);
        *reinterpret_cast<ushort4*>(dp + 4) = *reinterpret_cast<ushort4*>(&wt[li][ljb + 4]);
    }
}

// ---------------- conv1 (k-major MFMA): block 64o x 64n, y=(br,o_half) ----------------
// br==1 additionally writes C1 in packed bf16 fragment order.
__global__ __launch_bounds__(256) void k_conv1_mfma(const float* __restrict__ Zcur,
                                                    const unsigned short* __restrict__ Wh,
                                                    const unsigned short* __restrict__ Wl,
                                                    const float* __restrict__ bksl,
                                                    const float* __restrict__ mask,
                                                    float* __restrict__ C0,
                                                    float* __restrict__ C1,
                                                    unsigned short* __restrict__ C1pk) {
    __shared__ __align__(16) unsigned short xh[80][64];
    __shared__ __align__(16) unsigned short xl[80][64];
    int n0 = blockIdx.x * 64;
    int y = blockIdx.y;
    int b = blockIdx.z;
    int br = y >> 1, half = y & 1;
    int tid = threadIdx.x;
    const float* Xb = Zcur + (size_t)b * CH * NN;

    for (int e = tid; e < 64 * 20; e += 256) {
        int i = e / 20, t = e - i * 20;
        int gn = n0 + t * 4 - 4;
        float4 v = make_float4(0.f, 0.f, 0.f, 0.f);
        if (gn >= 0 && gn + 3 < NN) v = *reinterpret_cast<const float4*>(&Xb[(size_t)i * NN + gn]);
        float vv[4] = {v.x, v.y, v.z, v.w};
#pragma unroll
        for (int j = 0; j < 4; ++j) {
            int row = t * 4 + j;
            int col = i ^ ((row & 7) << 3);
            unsigned short h = f2bf(vv[j]);
            xh[row][col] = h;
            xl[row][col] = f2bf(vv[j] - bf2f(h));
        }
    }
    __syncthreads();

    int wid = tid >> 6, lane = tid & 63;
    int wo = (wid >> 1) * 32, wn = (wid & 1) * 32;
    int r = lane & 15, g = lane >> 4;
    int r32 = half * 2 + (wid >> 1);
    size_t brOff = (size_t)br * (CC / 32) * (576 / 32) * 1024;

    f32x4 acc[2][2] = {};
#pragma unroll 3
    for (int q = 0; q < 18; ++q) {
        int k = q >> 1, s = q & 1;
        size_t widx = brOff + ((size_t)(r32 * 18 + q)) * 1024 + lane * 8;
        bf16x8 ah[2], al[2];
        ah[0] = *reinterpret_cast<const bf16x8*>(&Wh[widx]);
        ah[1] = *reinterpret_cast<const bf16x8*>(&Wh[widx + 512]);
        al[0] = *reinterpret_cast<const bf16x8*>(&Wl[widx]);
        al[1] = *reinterpret_cast<const bf16x8*>(&Wl[widx + 512]);
        bf16x8 bh[2], bl[2];
#pragma unroll
        for (int fn = 0; fn < 2; ++fn) {
            int row = wn + fn * 16 + r + k;
            int chs = (s * 32 + g * 8) ^ ((row & 7) << 3);
            bh[fn] = *reinterpret_cast<const bf16x8*>(&xh[row][chs]);
            bl[fn] = *reinterpret_cast<const bf16x8*>(&xl[row][chs]);
        }
#pragma unroll
        for (int fc = 0; fc < 2; ++fc)
#pragma unroll
            for (int fn = 0; fn < 2; ++fn) {
                acc[fc][fn] = __builtin_amdgcn_mfma_f32_16x16x32_bf16(ah[fc], bh[fn], acc[fc][fn], 0, 0, 0);
                acc[fc][fn] = __builtin_amdgcn_mfma_f32_16x16x32_bf16(al[fc], bh[fn], acc[fc][fn], 0, 0, 0);
                acc[fc][fn] = __builtin_amdgcn_mfma_f32_16x16x32_bf16(ah[fc], bl[fn], acc[fc][fn], 0, 0, 0);
            }
    }

    const float* mkB = mask + b * NN;
    float* Outp = (br ? C1 : C0) + ((size_t)b * CC + half * 64) * NN;
    const float* bo_base = bksl + (br * CC + half * 64) * KS;
#pragma unroll
    for (int fc = 0; fc < 2; ++fc) {
#pragma unroll
        for (int fn = 0; fn < 2; ++fn) {
            int n = n0 + wn + fn * 16 + r;
#pragma unroll
            for (int rr = 0; rr < 4; ++rr) {
                int oo = wo + fc * 16 + 4 * g + rr;
                float v = acc[fc][fn][rr];
                const float* bo = bo_base + oo * KS;
                float bias = 0.f;
#pragma unroll
                for (int k = 0; k < KS; ++k) {
                    int nn2 = n + k - 4;
                    if (nn2 >= 0 && nn2 < NN) bias += bo[k];
                }
                v += bias;
                if (br == 0) v *= mkB[n];
                Outp[(size_t)oo * NN + n] = v;
                if (br == 1) {
                    int cg = half * 64 + oo;
                    int chunk = ((b * 4 + (cg >> 5)) * 32 + (n >> 5)) * 2 + ((cg >> 4) & 1);
                    int lane2 = ((n >> 3) & 3) * 16 + (cg & 15);
                    C1pk[((size_t)chunk * 64 + lane2) * 8 + (n & 7)] = f2bf(v);
                }
            }
        }
    }
}

// ---------------- conv1T (k-major MFMA): block 64i x 32n, y=br; in-block split-K ----------------
// Colnorm fully local: stages (x-mean)*mask fp32, computes per-column inv in-block,
// applies relu(v*inv) during hi/lo packing. br==1 additionally writes T1p packed bf16.
__global__ __launch_bounds__(256) void k_convT_mfma(const float* __restrict__ C0,
                                                    const float* __restrict__ A1,
                                                    const unsigned short* __restrict__ Wh,
                                                    const unsigned short* __restrict__ Wl,
                                                    const float* __restrict__ mask,
                                                    const float* __restrict__ meanA,
                                                    float* __restrict__ T0,
                                                    float* __restrict__ T1p,
                                                    unsigned short* __restrict__ T1pk) {
    __shared__ float fs[48][132];
    __shared__ __align__(16) unsigned short xh[48][128];
    __shared__ __align__(16) unsigned short xl[48][128];
    __shared__ float red2[2][32][33];
    __shared__ float ps[48][4];
    __shared__ float invc[48];
    int n0 = blockIdx.x * 32;
    int br = blockIdx.y;
    int b = blockIdx.z;
    int tid = threadIdx.x;
    const float* Xb = (br ? A1 : C0) + (size_t)b * CC * NN;
    const float* meB = meanA + ((size_t)br * BB + b) * CC;
    const float* mkB = mask + b * NN;

    // pass 1: stage raw (x - mean)*mask (fp32)
    for (int e = tid; e < 128 * 12; e += 256) {
        int i = e / 12, t = e - i * 12;
        int gn = n0 + t * 4 - 4;
        float4 v = make_float4(0.f, 0.f, 0.f, 0.f);
        if (gn >= 0 && gn + 3 < NN) {
            v = *reinterpret_cast<const float4*>(&Xb[(size_t)i * NN + gn]);
            float me = meB[i];
            float4 mk = *reinterpret_cast<const float4*>(&mkB[gn]);
            v.x = (v.x - me) * mk.x;
            v.y = (v.y - me) * mk.y;
            v.z = (v.z - me) * mk.z;
            v.w = (v.w - me) * mk.w;
        }
        fs[t * 4 + 0][i] = v.x;
        fs[t * 4 + 1][i] = v.y;
        fs[t * 4 + 2][i] = v.z;
        fs[t * 4 + 3][i] = v.w;
    }
    __syncthreads();
    // pass 2: per-column (n) sums over 128 channels -> inv
    if (tid < 192) {
        int row = tid % 48, seg = tid / 48;
        float ss = 0.f;
#pragma unroll
        for (int i = 0; i < 32; ++i) { float v = fs[row][seg * 32 + i]; ss += v * v; }
        ps[row][seg] = ss;
    }
    __syncthreads();
    if (tid < 48) invc[tid] = rsqrtf(ps[tid][0] + ps[tid][1] + ps[tid][2] + ps[tid][3] + 0.001f);
    __syncthreads();
    // pass 3: relu(v*inv), hi/lo pack with XOR swizzle
    for (int e = tid; e < 128 * 12; e += 256) {
        int i = e / 12, t = e - i * 12;
#pragma unroll
        for (int j = 0; j < 4; ++j) {
            int row = t * 4 + j;
            float v = fmaxf(fs[row][i] * invc[row], 0.f);
            int col = i ^ ((row & 7) << 3);
            unsigned short h = f2bf(v);
            xh[row][col] = h;
            xl[row][col] = f2bf(v - bf2f(h));
        }
    }
    __syncthreads();

    int wid = tid >> 6, lane = tid & 63;
    int i32 = wid & 1, kh = wid >> 1;
    int r = lane & 15, g = lane >> 4;
    size_t brW = (size_t)br * (CH / 32) * (1152 / 32) * 1024;

    f32x4 acc[2][2] = {};
#pragma unroll 3
    for (int t = 0; t < 18; ++t) {
        int k = t >> 1, s = kh * 2 + (t & 1);
        int q32 = k * 4 + s;
        size_t widx = brW + ((size_t)(i32 * 36 + q32)) * 1024 + lane * 8;
        bf16x8 ah[2], al[2];
        ah[0] = *reinterpret_cast<const bf16x8*>(&Wh[widx]);
        ah[1] = *reinterpret_cast<const bf16x8*>(&Wh[widx + 512]);
        al[0] = *reinterpret_cast<const bf16x8*>(&Wl[widx]);
        al[1] = *reinterpret_cast<const bf16x8*>(&Wl[widx + 512]);
        bf16x8 bh[2], bl[2];
#pragma unroll
        for (int fn = 0; fn < 2; ++fn) {
            int row = fn * 16 + r + k;
            int chs = (s * 32 + g * 8) ^ ((row & 7) << 3);
            bh[fn] = *reinterpret_cast<const bf16x8*>(&xh[row][chs]);
            bl[fn] = *reinterpret_cast<const bf16x8*>(&xl[row][chs]);
        }
#pragma unroll
        for (int fc = 0; fc < 2; ++fc)
#pragma unroll
            for (int fn = 0; fn < 2; ++fn) {
                acc[fc][fn] = __builtin_amdgcn_mfma_f32_16x16x32_bf16(ah[fc], bh[fn], acc[fc][fn], 0, 0, 0);
                acc[fc][fn] = __builtin_amdgcn_mfma_f32_16x16x32_bf16(al[fc], bh[fn], acc[fc][fn], 0, 0, 0);
                acc[fc][fn] = __builtin_amdgcn_mfma_f32_16x16x32_bf16(ah[fc], bl[fn], acc[fc][fn], 0, 0, 0);
            }
    }

    if (kh == 1) {
#pragma unroll
        for (int fc = 0; fc < 2; ++fc)
#pragma unroll
            for (int fn = 0; fn < 2; ++fn)
#pragma unroll
                for (int rr = 0; rr < 4; ++rr)
                    red2[i32][fc * 16 + 4 * g + rr][fn * 16 + r] = acc[fc][fn][rr];
    }
    __syncthreads();
    if (kh == 0) {
        float* Outp = (br ? T1p : T0) + (size_t)b * CH * NN;
#pragma unroll
        for (int fc = 0; fc < 2; ++fc)
#pragma unroll
            for (int fn = 0; fn < 2; ++fn) {
                int n = n0 + fn * 16 + r;
#pragma unroll
                for (int rr = 0; rr < 4; ++rr) {
                    int irow = fc * 16 + 4 * g + rr;
                    float v = acc[fc][fn][rr] + red2[i32][irow][fn * 16 + r];
                    Outp[(size_t)(i32 * 32 + irow) * NN + n] = v;
                    if (br == 1) {
                        int cg = i32 * 32 + irow;
                        int chunk = ((b * 2 + (cg >> 5)) * 32 + (n >> 5)) * 2 + ((cg >> 4) & 1);
                        int lane2 = ((n >> 3) & 3) * 16 + (cg & 15);
                        T1pk[((size_t)chunk * 64 + lane2) * 8 + (n & 7)] = f2bf(v);
                    }
                }
            }
    }
}

// ---------------- LDS-free MFMA split-K X@W partials (packed X, packed W) ----------------
template <int SKN>
__global__ __launch_bounds__(256) void k_matL_mfma(const unsigned short* __restrict__ Xpk,
                                                   const unsigned short* __restrict__ Wpk,
                                                   float* __restrict__ Part, int rows) {
    int cb = rows >> 6;
    int sk = blockIdx.y;
    int b = blockIdx.z / cb;
    int c0 = (blockIdx.z % cb) * 64;
    int tid = threadIdx.x;
    int wid = tid >> 6, lane = tid & 63;
    int wc = (wid >> 1) * 32;
    int r = lane & 15, g = lane >> 4;
    int rowsT = rows >> 5;
    int ct = (c0 >> 5) + (wid >> 1);
    int nt32 = blockIdx.x * 2 + (wid & 1);
    const unsigned short* Xb = Xpk + ((size_t)(b * rowsT + ct)) * 32768 + (size_t)lane * 8;
    const unsigned short* Wb = Wpk + ((size_t)(b * 32 + nt32)) * 32768 + (size_t)lane * 8;

    f32x4 acc[2][2] = {};
    int ms_beg = sk * (32 / SKN);
#pragma unroll 4
    for (int ms = ms_beg; ms < ms_beg + 32 / SKN; ++ms) {
        bf16x8 a0 = *reinterpret_cast<const bf16x8*>(&Xb[(size_t)ms * 1024]);
        bf16x8 a1 = *reinterpret_cast<const bf16x8*>(&Xb[(size_t)ms * 1024 + 512]);
        bf16x8 w0 = *reinterpret_cast<const bf16x8*>(&Wb[(size_t)ms * 1024]);
        bf16x8 w1 = *reinterpret_cast<const bf16x8*>(&Wb[(size_t)ms * 1024 + 512]);
        acc[0][0] = __builtin_amdgcn_mfma_f32_16x16x32_bf16(a0, w0, acc[0][0], 0, 0, 0);
        acc[0][1] = __builtin_amdgcn_mfma_f32_16x16x32_bf16(a0, w1, acc[0][1], 0, 0, 0);
        acc[1][0] = __builtin_amdgcn_mfma_f32_16x16x32_bf16(a1, w0, acc[1][0], 0, 0, 0);
        acc[1][1] = __builtin_amdgcn_mfma_f32_16x16x32_bf16(a1, w1, acc[1][1], 0, 0, 0);
    }
    int n0 = blockIdx.x * 64;
    int wn = (wid & 1) * 32;
#pragma unroll
    for (int fc = 0; fc < 2; ++fc)
#pragma unroll
        for (int fn = 0; fn < 2; ++fn) {
            int ncol = n0 + wn + fn * 16 + r;
#pragma unroll
            for (int rr = 0; rr < 4; ++rr) {
                int crow = c0 + wc + fc * 16 + 4 * g + rr;
                Part[(((size_t)b * SKN + sk) * rows + crow) * NN + ncol] = acc[fc][fn][rr];
            }
        }
}

// ---------------- reduce partials + epilogue (block = one (b,c) row) ----------------
// MODE 0: Out = (X*Wsum - sumPart)*mask ; writes meanA[z1] (A1 rowmean) AND meanA[z0] (C0 rowmean).
// MODE 1: Out -= H*mask*(T0 + X*Wsum - sumPart)
template <int SKN, int MODE>
__global__ __launch_bounds__(256) void k_matL_fin(const float* __restrict__ X,
                                                  const float* __restrict__ Part,
                                                  const float* __restrict__ Wsum,
                                                  const float* __restrict__ mask,
                                                  const float* __restrict__ T0,
                                                  float* __restrict__ Out,
                                                  float* __restrict__ meanA, int rows,
                                                  const float* __restrict__ C0p) {
    __shared__ float red[256];
    int c = blockIdx.x, b = blockIdx.y;
    int n = threadIdx.x * 4;
    float4 s = make_float4(0.f, 0.f, 0.f, 0.f);
#pragma unroll
    for (int sk = 0; sk < SKN; ++sk) {
        float4 p = *reinterpret_cast<const float4*>(
            &Part[(((size_t)b * SKN + sk) * rows + c) * NN + n]);
        s.x += p.x; s.y += p.y; s.z += p.z; s.w += p.w;
    }
    float4 xv = *reinterpret_cast<const float4*>(&X[((size_t)b * rows + c) * NN + n]);
    float4 wv = *reinterpret_cast<const float4*>(&Wsum[b * NN + n]);
    float4 mv = *reinterpret_cast<const float4*>(&mask[b * NN + n]);
    float y0 = xv.x * wv.x - s.x, y1 = xv.y * wv.y - s.y;
    float y2 = xv.z * wv.z - s.z, y3 = xv.w * wv.w - s.w;
    if (MODE == 0) {
        float4 res = make_float4(y0 * mv.x, y1 * mv.y, y2 * mv.z, y3 * mv.w);
        *reinterpret_cast<float4*>(&Out[((size_t)b * rows + c) * NN + n]) = res;
        float4 c0v = *reinterpret_cast<const float4*>(&C0p[((size_t)b * rows + c) * NN + n]);
        float rs = res.x * mv.x + res.y * mv.y + res.z * mv.z + res.w * mv.w;
        float cs = c0v.x * mv.x + c0v.y * mv.y + c0v.z * mv.z + c0v.w * mv.w;
        float ms = mv.x + mv.y + mv.z + mv.w;
        rs = blockSum(rs, red);
        cs = blockSum(cs, red);
        ms = blockSum(ms, red);
        if (threadIdx.x == 0) {
            meanA[(size_t)b * CC + c] = cs / ms;              // z0: C0 rowmean
            meanA[((size_t)BB + b) * CC + c] = rs / ms;        // z1: A1 rowmean
        }
    } else {
        float4 t0 = *reinterpret_cast<const float4*>(&T0[((size_t)b * rows + c) * NN + n]);
        float4 o = *reinterpret_cast<const float4*>(&Out[((size_t)b * rows + c) * NN + n]);
        float4 res = make_float4(o.x - HSTEP * mv.x * (t0.x + y0),
                                 o.y - HSTEP * mv.y * (t0.y + y1),
                                 o.z - HSTEP * mv.z * (t0.z + y2),
                                 o.w - HSTEP * mv.w * (t0.w + y3));
        *reinterpret_cast<float4*>(&Out[((size_t)b * rows + c) * NN + n]) = res;
    }
}

// ---------------- close ----------------
__global__ __launch_bounds__(256) void k_close(const float* __restrict__ Zcur,
                                               const float* __restrict__ Kcl,
                                               const float* __restrict__ mask,
                                               float* __restrict__ Zout) {
    __shared__ float red[4][64][COUT];
    int tid = threadIdx.x;
    int nl = tid & 63, cg = tid >> 6;
    int n = blockIdx.x * 64 + nl;
    int b = blockIdx.y;
    float acc[COUT] = {};
#pragma unroll
    for (int cc = 0; cc < 16; ++cc) {
        int c = cg * 16 + cc;
        float zv = Zcur[((size_t)b * CH + c) * NN + n];
#pragma unroll
        for (int o = 0; o < COUT; ++o) acc[o] += Kcl[o * CH + c] * zv;
    }
#pragma unroll
    for (int o = 0; o < COUT; ++o) red[cg][nl][o] = acc[o];
    __syncthreads();
    if (cg == 0) {
        float mv = mask[b * NN + n];
#pragma unroll
        for (int o = 0; o < COUT; ++o) {
            float s = red[0][nl][o] + red[1][nl][o] + red[2][nl][o] + red[3][nl][o];
            Zout[((size_t)b * COUT + o) * NN + n] = s * mv;
        }
    }
}

// ---------------- center3 ----------------
__global__ __launch_bounds__(256) void k_center3(const float* __restrict__ Zout, float* __restrict__ Zc3) {
    __shared__ float red[256];
    int c = blockIdx.x, b = blockIdx.y, tid = threadIdx.x;
    const float* src = Zout + ((size_t)b * COUT + c) * NN;
    float s = 0.f;
    for (int n = tid; n < NN; n += 256) s += src[n];
    float mean = blockSum(s, red) / (float)NN;
    float* dst = Zc3 + ((size_t)b * COUT + c) * NN;
    for (int n = tid; n < NN; n += 256) dst[n] = src[n] - mean;
}

// ---------------- final pairwise distances (n2 computed from staged tiles) ----------------
__global__ __launch_bounds__(256) void k_dist(const float* __restrict__ Zc3,
                                              float* __restrict__ dout) {
    __shared__ float Ai[3][64], Aj[3][64], ni[64], nj[64];
    int bg = blockIdx.z;
    int b = bg / 3, g = bg - 3 * b;
    int i0 = blockIdx.x * 64, j0 = blockIdx.y * 64;
    int tid = threadIdx.x;
    for (int e = tid; e < 192; e += 256) {
        int c = e / 64, t = e - c * 64;
        Ai[c][t] = Zc3[((size_t)b * COUT + g * 3 + c) * NN + i0 + t];
    }
    for (int e = tid; e < 192; e += 256) {
        int c = e / 64, t = e - c * 64;
        Aj[c][t] = Zc3[((size_t)b * COUT + g * 3 + c) * NN + j0 + t];
    }
    __syncthreads();
    if (tid < 64) {
        ni[tid] = Ai[0][tid] * Ai[0][tid] + Ai[1][tid] * Ai[1][tid] + Ai[2][tid] * Ai[2][tid];
    } else if (tid < 128) {
        int t = tid - 64;
        nj[t] = Aj[0][t] * Aj[0][t] + Aj[1][t] * Aj[1][t] + Aj[2][t] * Aj[2][t];
    }
    __syncthreads();
    int tx = tid & 15, ty = tid >> 4;
    for (int q = 0; q < 4; ++q) {
        int i = ty * 4 + q;
        float a0 = Ai[0][i], a1 = Ai[1][i], a2 = Ai[2][i], n2i = ni[i];
        float res[4];
#pragma unroll
        for (int r = 0; r < 4; ++r) {
            int j = tx * 4 + r;
            float D = n2i + nj[j] - 2.f * (a0 * Aj[0][j] + a1 * Aj[1][j] + a2 * Aj[2][j]);
            D = fmaxf(D, 0.f);
            res[r] = (D > 0.f) ? sqrtf(D) : 0.f;
        }
        *reinterpret_cast<float4*>(&dout[(((size_t)b * 3 + g) * NN + i0 + i) * NN + j0 + tx * 4]) =
            *reinterpret_cast<float4*>(res);
    }
}

// ---------------- driver ----------------
extern "C" void kernel_launch(void* const* d_in, const int* in_sizes, int n_in,
                              void* d_out, int out_size, void* d_ws, size_t ws_size,
                              hipStream_t stream) {
    (void)in_sizes; (void)n_in; (void)out_size; (void)ws_size;
    const float* Zin  = (const float*)d_in[0];
    const float* mask = (const float*)d_in[1];
    const float* Kop  = (const float*)d_in[2];
    const float* Kcl  = (const float*)d_in[3];
    const float* Win  = (const float*)d_in[4];
    const float* Bias = (const float*)d_in[5];
    float* out = (float*)d_out;
    float* ws = (float*)d_ws;

    size_t off = 0;
    float* Zcur = ws + off;  off += (size_t)BB * CH * NN;
    float* C0   = ws + off;  off += (size_t)BB * CC * NN;
    float* C1   = ws + off;  off += (size_t)BB * CC * NN;
    float* A1   = ws + off;  off += (size_t)BB * CC * NN;
    float* T0   = ws + off;  off += (size_t)BB * CH * NN;
    float* T1p  = ws + off;  off += (size_t)BB * CH * NN;
    float* Za   = ws + off;  off += (size_t)BB * 65 * NN;
    float* Wsum = ws + off;  off += (size_t)BB * NN;
    float* meanA= ws + off;  off += (size_t)2 * BB * CC;
    float* bks  = ws + off;  off += (size_t)NL * 2 * CC * KS;
    float* Zc3  = ws + off;  off += (size_t)BB * COUT * NN;

    // Scratch in the (as-yet-unwritten) dists region of d_out (25,165,824 floats):
    float* Part = out;                                                   // [0 .. 2,097,152)
    unsigned short* Wpk2  = (unsigned short*)(out + (size_t)4194304);    // [.. 8,388,608)
    unsigned short* C1pk  = (unsigned short*)(out + (size_t)8388608);    // 1,048,576 shorts
    unsigned short* T1pk  = (unsigned short*)(out + (size_t)8912896);    // 524,288 shorts
    unsigned short* PKc_h = (unsigned short*)(out + (size_t)14680064);
    unsigned short* PKc_l = (unsigned short*)(out + (size_t)15417344);
    unsigned short* PKt_h = (unsigned short*)(out + (size_t)16154624);
    unsigned short* PKt_l = (unsigned short*)(out + (size_t)16891904);   // ends 17,629,184

    const int wtot = NL * 2 * CC * CH * KS;
    k_prep_wbf<<<dim3((wtot + 255) / 256), 256, 0, stream>>>(Win, PKc_h, PKc_l, PKt_h, PKt_l);
    k_prep_bks<<<dim3((NL * 2 * CC * KS + 255) / 256), 256, 0, stream>>>(Win, Bias, bks);
    k_zero<<<dim3(BB * NN / 256), 256, 0, stream>>>(Wsum, BB * NN);
    k_open<<<dim3(NN / 256, CH, BB), 256, 0, stream>>>(Zin, mask, Kop, Zcur);
    k_za<<<dim3(65, BB), 256, 0, stream>>>(Zcur, mask, Za);
    k_gramW<<<dim3(16, 16, BB), 256, 0, stream>>>(Za, mask, Wpk2, Wsum);

    for (int l = 0; l < NL; ++l) {
        const unsigned short* PKc_h_l = PKc_h + (size_t)l * 2 * CC * 576;
        const unsigned short* PKc_l_l = PKc_l + (size_t)l * 2 * CC * 576;
        const unsigned short* PKt_h_l = PKt_h + (size_t)l * 2 * CH * 1152;
        const unsigned short* PKt_l_l = PKt_l + (size_t)l * 2 * CH * 1152;
        const float* bksl = bks + (size_t)l * 2 * CC * KS;

        k_conv1_mfma<<<dim3(NN / 64, 4, BB), 256, 0, stream>>>(
            Zcur, PKc_h_l, PKc_l_l, bksl, mask, C0, C1, C1pk);
        k_matL_mfma<SKC><<<dim3(NN / 64, SKC, BB * (CC / 64)), 256, 0, stream>>>(C1pk, Wpk2, Part, CC);
        k_matL_fin<SKC, 0><<<dim3(CC, BB), 256, 0, stream>>>(
            C1, Part, Wsum, mask, nullptr, A1, meanA, CC, C0);
        k_convT_mfma<<<dim3(NN / 32, 2, BB), 256, 0, stream>>>(
            C0, A1, PKt_h_l, PKt_l_l, mask, meanA, T0, T1p, T1pk);
        k_matL_mfma<SKH><<<dim3(NN / 64, SKH, BB * (CH / 64)), 256, 0, stream>>>(T1pk, Wpk2, Part, CH);
        k_matL_fin<SKH, 1><<<dim3(CH, BB), 256, 0, stream>>>(
            T1p, Part, Wsum, mask, T0, Zcur, nullptr, CH, nullptr);
    }

    float* Zout = out + (size_t)BB * 3 * NN * NN;
    k_close<<<dim3(NN / 64, BB), 256, 0, stream>>>(Zcur, Kcl, mask, Zout);
    k_center3<<<dim3(COUT, BB), 256, 0, stream>>>(Zout, Zc3);
    k_dist<<<dim3(16, 16, 3 * BB), 256, 0, stream>>>(Zc3, out);
}

// Round 14
// 771.908 us; speedup vs baseline: 1.3276x; 1.0593x over previous
//
#include <hip/hip_runtime.h>
#include <cstddef>

#define BB 8
#define NN 1024
#define CIN 40
#define CH 64
#define CC 128
#define COUT 9
#define KS 9
#define NL 10
#define HSTEP 0.1f

typedef __attribute__((ext_vector_type(8))) short bf16x8;
typedef __attribute__((ext_vector_type(4))) float f32x4;

__device__ __forceinline__ unsigned short f2bf(float f) {
    union { float f; unsigned u; } v;
    v.f = f;
    unsigned u = v.u;
    u += 0x7FFFu + ((u >> 16) & 1u);
    return (unsigned short)(u >> 16);
}
__device__ __forceinline__ float bf2f(unsigned short h) {
    union { unsigned u; float f; } v;
    v.u = ((unsigned)h) << 16;
    return v.f;
}

// packed-fragment address (chunk = 64 lanes x 8 shorts = 512 shorts):
// chunk=((lb*(R/32)+row>>5)*(KDv/32)+col>>5)*2+((row>>4)&1), lane=((col>>3)&3)*16+(row&15)
__device__ __forceinline__ size_t pk_addr(int lb, int row, int col, int R, int KDv) {
    int chunk = ((lb * (R / 32) + (row >> 5)) * (KDv / 32) + (col >> 5)) * 2 + ((row >> 4) & 1);
    int lane = ((col >> 3) & 3) * 16 + (row & 15);
    return ((size_t)chunk * 64 + lane) * 8 + (col & 7);
}

// ---------------- helpers ----------------
__device__ __forceinline__ float blockSum(float v, float* red) {
    int tid = threadIdx.x;
    red[tid] = v;
    __syncthreads();
    for (int s = 128; s > 0; s >>= 1) {
        if (tid < s) red[tid] += red[tid + s];
        __syncthreads();
    }
    float r = red[0];
    __syncthreads();
    return r;
}

__global__ __launch_bounds__(256) void k_zero(float* __restrict__ p, int n) {
    int i = blockIdx.x * 256 + threadIdx.x;
    if (i < n) p[i] = 0.f;
}

__global__ __launch_bounds__(256) void k_msum(const float* __restrict__ mask,
                                              float* __restrict__ msum) {
    __shared__ float red[256];
    int b = blockIdx.x, tid = threadIdx.x;
    float s = 0.f;
    for (int n = tid; n < NN; n += 256) s += mask[b * NN + n];
    s = blockSum(s, red);
    if (tid == 0) msum[b] = s;
}

// ---------------- conv weights -> packed fragments, k-major contraction, hi/lo ----------------
__global__ __launch_bounds__(256) void k_prep_wbf(const float* __restrict__ Win,
                                                  unsigned short* __restrict__ PKc_h,
                                                  unsigned short* __restrict__ PKc_l,
                                                  unsigned short* __restrict__ PKt_h,
                                                  unsigned short* __restrict__ PKt_l) {
    int idx = blockIdx.x * 256 + threadIdx.x;
    const int total = NL * 2 * CC * CH * KS;
    if (idx >= total) return;
    int k = idx % KS;
    int t = idx / KS;
    int i = t % CH;  t /= CH;
    int o = t % CC;  t /= CC;
    int lb = t;
    float v = Win[idx];
    unsigned short h = f2bf(v);
    unsigned short l = f2bf(v - bf2f(h));
    size_t ac = pk_addr(lb, o, k * 64 + i, CC, 576);
    size_t at = pk_addr(lb, i, (8 - k) * 128 + o, CH, 1152);
    PKc_h[ac] = h;
    PKc_l[ac] = l;
    PKt_h[at] = h;
    PKt_l[at] = l;
}

// bks[lb][o][k] = sum_i Win[lb][o][i][k] * Bias[lb][i]
__global__ __launch_bounds__(256) void k_prep_bks(const float* __restrict__ Win,
                                                  const float* __restrict__ Bias,
                                                  float* __restrict__ bks) {
    int idx = blockIdx.x * 256 + threadIdx.x;
    const int total = NL * 2 * CC * KS;
    if (idx >= total) return;
    int k = idx % KS;
    int t = idx / KS;
    int o = t % CC;
    int lb = t / CC;
    float s = 0.f;
    for (int i = 0; i < CH; ++i)
        s += Win[(((size_t)lb * CC + o) * CH + i) * KS + k] * Bias[lb * CH + i];
    bks[idx] = s;
}

// ---------------- open ----------------
__global__ __launch_bounds__(256) void k_open(const float* __restrict__ Zin,
                                              const float* __restrict__ mask,
                                              const float* __restrict__ Kop,
                                              float* __restrict__ Zcur) {
    int n = blockIdx.x * 256 + threadIdx.x;
    int c = blockIdx.y, b = blockIdx.z;
    float acc = 0.f;
    for (int i = 0; i < CIN; ++i)
        acc += Kop[c * CIN + i] * Zin[((size_t)b * CIN + i) * NN + n];
    Zcur[((size_t)b * CH + c) * NN + n] = acc * mask[b * NN + n];
}

// ---------------- Za ----------------
__global__ __launch_bounds__(256) void k_za(const float* __restrict__ Zcur,
                                            const float* __restrict__ mask,
                                            float* __restrict__ Za) {
    __shared__ float red[256];
    int c = blockIdx.x;  // 0..64
    int b = blockIdx.y;
    int tid = threadIdx.x;
    const float* m = mask + b * NN;
    float x[4], mv[4];
    if (c < CH) {
        const float* src = Zcur + ((size_t)b * CH + c) * NN;
#pragma unroll
        for (int j = 0; j < 4; ++j) { int n = tid * 4 + j; x[j] = src[n]; mv[j] = m[n]; }
    } else {
#pragma unroll
        for (int j = 0; j < 4; ++j) { int n = tid * 4 + j; mv[j] = m[n]; x[j] = 0.5f * ((float)n / 1023.f) * mv[j]; }
    }
    float sm = 0.f, sxm = 0.f;
#pragma unroll
    for (int j = 0; j < 4; ++j) { sm += mv[j]; sxm += x[j] * mv[j]; }
    float msum = blockSum(sm, red);
    float xm = blockSum(sxm, red);
    if (c < CH) {
        float mean = xm / msum;
        float ss = 0.f;
#pragma unroll
        for (int j = 0; j < 4; ++j) { x[j] -= mean * mv[j]; ss += x[j] * x[j]; }
        ss = blockSum(ss, red);
        float sc = rsqrtf(ss / msum + 1e-4f);
#pragma unroll
        for (int j = 0; j < 4; ++j) x[j] *= sc;
    }
    float ps = 0.f;
#pragma unroll
    for (int j = 0; j < 4; ++j) ps += x[j];
    float pm = blockSum(ps, red) / (float)NN;
    float* dst = Za + ((size_t)b * 65 + c) * NN;
#pragma unroll
    for (int j = 0; j < 4; ++j) dst[tid * 4 + j] = x[j] - pm;
}

// ---------------- Gram + W: local n2, writes packed bf16 W + atomic fp32 Wsum ----------------
__global__ __launch_bounds__(256) void k_gramW(const float* __restrict__ Za,
                                               const float* __restrict__ mask,
                                               unsigned short* __restrict__ Wpk,
                                               float* __restrict__ Wsum) {
    __shared__ float As[65][68];
    __shared__ float Bs2[65][68];
    __shared__ unsigned short wt[64][72];
    __shared__ float csred[16][64];
    __shared__ float n2is[64], n2js[64];
    int i0 = blockIdx.x * 64, j0 = blockIdx.y * 64, b = blockIdx.z;
    int tid = threadIdx.x;
    for (int e = tid; e < 65 * 64; e += 256) {
        int c = e >> 6, t = e & 63;
        const float* src = Za + ((size_t)b * 65 + c) * NN;
        As[c][t] = src[i0 + t];
        Bs2[c][t] = src[j0 + t];
    }
    __syncthreads();
    if (tid < 64) {
        float s = 0.f;
        for (int c = 0; c < 65; ++c) { float v = As[c][tid]; s += v * v; }
        n2is[tid] = s;
    } else if (tid < 128) {
        int t = tid - 64;
        float s = 0.f;
        for (int c = 0; c < 65; ++c) { float v = Bs2[c][t]; s += v * v; }
        n2js[t] = s;
    }
    __syncthreads();
    int tx = tid & 15, ty = tid >> 4;
    float acc[4][4] = {};
    for (int c = 0; c < 65; ++c) {
        float a[4];
#pragma unroll
        for (int q = 0; q < 4; ++q) a[q] = As[c][ty * 4 + q];
        float bv[4];
        *reinterpret_cast<float4*>(bv) = *reinterpret_cast<const float4*>(&Bs2[c][tx * 4]);
#pragma unroll
        for (int q = 0; q < 4; ++q)
#pragma unroll
            for (int r = 0; r < 4; ++r) acc[q][r] += a[q] * bv[r];
    }
    const float* m = mask + b * NN;
    float csacc[4] = {0.f, 0.f, 0.f, 0.f};
    for (int q = 0; q < 4; ++q) {
        int i = i0 + ty * 4 + q;
        float n2i = n2is[ty * 4 + q], mi = m[i];
#pragma unroll
        for (int r = 0; r < 4; ++r) {
            int j = j0 + tx * 4 + r;
            float D = n2i + n2js[tx * 4 + r] - 2.f * acc[q][r];
            D *= (3.f / 65.f);
            D = fmaxf(D, 0.f);
            float dist = (D > 0.f) ? sqrtf(D) : 0.f;
            float mmv = mi * m[j];
            float res = expf(-dist * mmv) * mmv;
            wt[ty * 4 + q][tx * 4 + r] = f2bf(res);
            csacc[r] += res;
        }
    }
#pragma unroll
    for (int r = 0; r < 4; ++r) csred[ty][tx * 4 + r] = csacc[r];
    __syncthreads();
    for (int s = 8; s > 0; s >>= 1) {
        if (ty < s) {
#pragma unroll
            for (int r = 0; r < 4; ++r) csred[ty][tx * 4 + r] += csred[ty + s][tx * 4 + r];
        }
        __syncthreads();
    }
    if (ty == 0) {
#pragma unroll
        for (int r = 0; r < 4; ++r)
            atomicAdd(&Wsum[b * NN + j0 + tx * 4 + r], csred[0][tx * 4 + r]);
    }
    for (int e = tid; e < 512; e += 256) {
        int li = e >> 3, ljb = (e & 7) * 8;
        int row = i0 + li, col = j0 + ljb;
        int chunk = ((b * 32 + (row >> 5)) * 32 + (col >> 5)) * 2 + ((row >> 4) & 1);
        int lane2 = ((col >> 3) & 3) * 16 + (row & 15);
        unsigned short* dp = Wpk + ((size_t)chunk * 64 + lane2) * 8;
        *reinterpret_cast<ushort4*>(dp) = *reinterpret_cast<ushort4*>(&wt[li][ljb]);
        *reinterpret_cast<ushort4*>(dp + 4) = *reinterpret_cast<ushort4*>(&wt[li][ljb + 4]);
    }
}

// ---------------- conv1 (k-major MFMA): block 64o x 64n, y=(br,o_half) ----------------
// br==0 emits meanP0[b][c][nt16] masked row-partials; br==1 emits C1pk packed bf16.
__global__ __launch_bounds__(256) void k_conv1_mfma(const float* __restrict__ Zcur,
                                                    const unsigned short* __restrict__ Wh,
                                                    const unsigned short* __restrict__ Wl,
                                                    const float* __restrict__ bksl,
                                                    const float* __restrict__ mask,
                                                    float* __restrict__ C0,
                                                    float* __restrict__ C1,
                                                    unsigned short* __restrict__ C1pk,
                                                    float* __restrict__ meanP0) {
    __shared__ __align__(16) unsigned short xh[80][64];
    __shared__ __align__(16) unsigned short xl[80][64];
    __shared__ float rs[64][2];
    int n0 = blockIdx.x * 64;
    int y = blockIdx.y;
    int b = blockIdx.z;
    int br = y >> 1, half = y & 1;
    int tid = threadIdx.x;
    const float* Xb = Zcur + (size_t)b * CH * NN;

    for (int e = tid; e < 64 * 20; e += 256) {
        int i = e / 20, t = e - i * 20;
        int gn = n0 + t * 4 - 4;
        float4 v = make_float4(0.f, 0.f, 0.f, 0.f);
        if (gn >= 0 && gn + 3 < NN) v = *reinterpret_cast<const float4*>(&Xb[(size_t)i * NN + gn]);
        float vv[4] = {v.x, v.y, v.z, v.w};
#pragma unroll
        for (int j = 0; j < 4; ++j) {
            int row = t * 4 + j;
            int col = i ^ ((row & 7) << 3);
            unsigned short h = f2bf(vv[j]);
            xh[row][col] = h;
            xl[row][col] = f2bf(vv[j] - bf2f(h));
        }
    }
    __syncthreads();

    int wid = tid >> 6, lane = tid & 63;
    int wo = (wid >> 1) * 32, wn = (wid & 1) * 32;
    int r = lane & 15, g = lane >> 4;
    int r32 = half * 2 + (wid >> 1);
    size_t brOff = (size_t)br * (CC / 32) * (576 / 32) * 1024;

    f32x4 acc[2][2] = {};
#pragma unroll 3
    for (int q = 0; q < 18; ++q) {
        int k = q >> 1, s = q & 1;
        size_t widx = brOff + ((size_t)(r32 * 18 + q)) * 1024 + lane * 8;
        bf16x8 ah[2], al[2];
        ah[0] = *reinterpret_cast<const bf16x8*>(&Wh[widx]);
        ah[1] = *reinterpret_cast<const bf16x8*>(&Wh[widx + 512]);
        al[0] = *reinterpret_cast<const bf16x8*>(&Wl[widx]);
        al[1] = *reinterpret_cast<const bf16x8*>(&Wl[widx + 512]);
        bf16x8 bh[2], bl[2];
#pragma unroll
        for (int fn = 0; fn < 2; ++fn) {
            int row = wn + fn * 16 + r + k;
            int chs = (s * 32 + g * 8) ^ ((row & 7) << 3);
            bh[fn] = *reinterpret_cast<const bf16x8*>(&xh[row][chs]);
            bl[fn] = *reinterpret_cast<const bf16x8*>(&xl[row][chs]);
        }
#pragma unroll
        for (int fc = 0; fc < 2; ++fc)
#pragma unroll
            for (int fn = 0; fn < 2; ++fn) {
                acc[fc][fn] = __builtin_amdgcn_mfma_f32_16x16x32_bf16(ah[fc], bh[fn], acc[fc][fn], 0, 0, 0);
                acc[fc][fn] = __builtin_amdgcn_mfma_f32_16x16x32_bf16(al[fc], bh[fn], acc[fc][fn], 0, 0, 0);
                acc[fc][fn] = __builtin_amdgcn_mfma_f32_16x16x32_bf16(ah[fc], bl[fn], acc[fc][fn], 0, 0, 0);
            }
    }

    const float* mkB = mask + b * NN;
    float* Outp = (br ? C1 : C0) + ((size_t)b * CC + half * 64) * NN;
    const float* bo_base = bksl + (br * CC + half * 64) * KS;
    float p[2][4] = {};
#pragma unroll
    for (int fc = 0; fc < 2; ++fc) {
#pragma unroll
        for (int fn = 0; fn < 2; ++fn) {
            int n = n0 + wn + fn * 16 + r;
#pragma unroll
            for (int rr = 0; rr < 4; ++rr) {
                int oo = wo + fc * 16 + 4 * g + rr;
                float v = acc[fc][fn][rr];
                const float* bo = bo_base + oo * KS;
                float bias = 0.f;
#pragma unroll
                for (int k = 0; k < KS; ++k) {
                    int nn2 = n + k - 4;
                    if (nn2 >= 0 && nn2 < NN) bias += bo[k];
                }
                v += bias;
                if (br == 0) {
                    v *= mkB[n];
                    p[fc][rr] += v * mkB[n];
                }
                Outp[(size_t)oo * NN + n] = v;
                if (br == 1) {
                    int cg = half * 64 + oo;
                    int chunk = ((b * 4 + (cg >> 5)) * 32 + (n >> 5)) * 2 + ((cg >> 4) & 1);
                    int lane2 = ((n >> 3) & 3) * 16 + (cg & 15);
                    C1pk[((size_t)chunk * 64 + lane2) * 8 + (n & 7)] = f2bf(v);
                }
            }
        }
    }
    if (br == 0) {
#pragma unroll
        for (int fc = 0; fc < 2; ++fc)
#pragma unroll
            for (int rr = 0; rr < 4; ++rr) {
                float v = p[fc][rr];
                v += __shfl_xor(v, 1); v += __shfl_xor(v, 2);
                v += __shfl_xor(v, 4); v += __shfl_xor(v, 8);
                if (r == 0) rs[wo + fc * 16 + 4 * g + rr][wid & 1] = v;
            }
        __syncthreads();
        if (tid < 64)
            meanP0[((size_t)b * CC + half * 64 + tid) * 16 + blockIdx.x] = rs[tid][0] + rs[tid][1];
    }
}

// ---------------- fused CC matL: Y=C1@L epilogue in-kernel ----------------
// grid (NN/32, 1, BB*2); block 64c x 32n; waves: kh=wid>>1 K-half, ch=wid&1 c-half.
// A1 = (C1*Wsum - acc)*mask ; emits meanP1[b][c][nt32] masked row-partials.
__global__ __launch_bounds__(256) void k_matL_cc(const unsigned short* __restrict__ C1pk,
                                                 const unsigned short* __restrict__ Wpk,
                                                 const float* __restrict__ C1,
                                                 const float* __restrict__ Wsum,
                                                 const float* __restrict__ mask,
                                                 float* __restrict__ A1,
                                                 float* __restrict__ meanP1) {
    __shared__ float red2[2][32][33];
    int nt32 = blockIdx.x;
    int b = blockIdx.z >> 1, chalf = blockIdx.z & 1;
    int c0 = chalf * 64;
    int tid = threadIdx.x;
    int wid = tid >> 6, lane = tid & 63;
    int kh = wid >> 1, ch = wid & 1;
    int r = lane & 15, g = lane >> 4;
    int ct = chalf * 2 + ch;
    const unsigned short* Xb = C1pk + ((size_t)(b * 4 + ct)) * 32768 + (size_t)lane * 8;
    const unsigned short* Wb = Wpk + ((size_t)(b * 32 + nt32)) * 32768 + (size_t)lane * 8;

    f32x4 acc[2][2] = {};
#pragma unroll 4
    for (int ms = kh * 16; ms < kh * 16 + 16; ++ms) {
        bf16x8 a0 = *reinterpret_cast<const bf16x8*>(&Xb[(size_t)ms * 1024]);
        bf16x8 a1 = *reinterpret_cast<const bf16x8*>(&Xb[(size_t)ms * 1024 + 512]);
        bf16x8 w0 = *reinterpret_cast<const bf16x8*>(&Wb[(size_t)ms * 1024]);
        bf16x8 w1 = *reinterpret_cast<const bf16x8*>(&Wb[(size_t)ms * 1024 + 512]);
        acc[0][0] = __builtin_amdgcn_mfma_f32_16x16x32_bf16(a0, w0, acc[0][0], 0, 0, 0);
        acc[0][1] = __builtin_amdgcn_mfma_f32_16x16x32_bf16(a0, w1, acc[0][1], 0, 0, 0);
        acc[1][0] = __builtin_amdgcn_mfma_f32_16x16x32_bf16(a1, w0, acc[1][0], 0, 0, 0);
        acc[1][1] = __builtin_amdgcn_mfma_f32_16x16x32_bf16(a1, w1, acc[1][1], 0, 0, 0);
    }
    if (kh == 1) {
#pragma unroll
        for (int fc = 0; fc < 2; ++fc)
#pragma unroll
            for (int fn = 0; fn < 2; ++fn)
#pragma unroll
                for (int rr = 0; rr < 4; ++rr)
                    red2[ch][fc * 16 + 4 * g + rr][fn * 16 + r] = acc[fc][fn][rr];
    }
    __syncthreads();
    if (kh == 0) {
        const float* C1b = C1 + (size_t)b * CC * NN;
        float* A1b = A1 + (size_t)b * CC * NN;
        const float* mk = mask + b * NN;
        const float* wsB = Wsum + b * NN;
        float p[2][4] = {};
#pragma unroll
        for (int fc = 0; fc < 2; ++fc)
#pragma unroll
            for (int fn = 0; fn < 2; ++fn) {
                int ncol = nt32 * 32 + fn * 16 + r;
                float mkv = mk[ncol], wsv = wsB[ncol];
#pragma unroll
                for (int rr = 0; rr < 4; ++rr) {
                    int crow = c0 + ch * 32 + fc * 16 + 4 * g + rr;
                    float v = acc[fc][fn][rr] + red2[ch][fc * 16 + 4 * g + rr][fn * 16 + r];
                    float y = C1b[(size_t)crow * NN + ncol] * wsv - v;
                    float res = y * mkv;
                    A1b[(size_t)crow * NN + ncol] = res;
                    p[fc][rr] += res * mkv;
                }
            }
#pragma unroll
        for (int fc = 0; fc < 2; ++fc)
#pragma unroll
            for (int rr = 0; rr < 4; ++rr) {
                float v = p[fc][rr];
                v += __shfl_xor(v, 1); v += __shfl_xor(v, 2);
                v += __shfl_xor(v, 4); v += __shfl_xor(v, 8);
                if (r == 0)
                    meanP1[((size_t)b * CC + c0 + ch * 32 + fc * 16 + 4 * g + rr) * 32 + nt32] = v;
            }
    }
}

// ---------------- conv1T (k-major MFMA): block 64i x 32n, y=br; in-block split-K ----------------
// Colnorm fully local; meanA assembled from meanP0/meanP1 partials + msum.
// br==1 additionally writes T1p packed bf16.
__global__ __launch_bounds__(256) void k_convT_mfma(const float* __restrict__ C0,
                                                    const float* __restrict__ A1,
                                                    const unsigned short* __restrict__ Wh,
                                                    const unsigned short* __restrict__ Wl,
                                                    const float* __restrict__ mask,
                                                    const float* __restrict__ meanP0,
                                                    const float* __restrict__ meanP1,
                                                    const float* __restrict__ msum,
                                                    float* __restrict__ T0,
                                                    float* __restrict__ T1p,
                                                    unsigned short* __restrict__ T1pk) {
    __shared__ float fs[48][132];
    __shared__ __align__(16) unsigned short xh[48][128];
    __shared__ __align__(16) unsigned short xl[48][128];
    __shared__ float red2[2][32][33];
    __shared__ float ps[48][4];
    __shared__ float invc[48];
    __shared__ float meB_sh[128];
    int n0 = blockIdx.x * 32;
    int br = blockIdx.y;
    int b = blockIdx.z;
    int tid = threadIdx.x;
    const float* Xb = (br ? A1 : C0) + (size_t)b * CC * NN;
    const float* mkB = mask + b * NN;

    if (tid < 128) {
        float s = 0.f;
        if (br == 0) {
            const float* mp = meanP0 + ((size_t)b * CC + tid) * 16;
#pragma unroll
            for (int t = 0; t < 16; ++t) s += mp[t];
        } else {
            const float* mp = meanP1 + ((size_t)b * CC + tid) * 32;
#pragma unroll
            for (int t = 0; t < 32; ++t) s += mp[t];
        }
        meB_sh[tid] = s / msum[b];
    }
    __syncthreads();

    // pass 1: stage raw (x - mean)*mask (fp32)
    for (int e = tid; e < 128 * 12; e += 256) {
        int i = e / 12, t = e - i * 12;
        int gn = n0 + t * 4 - 4;
        float4 v = make_float4(0.f, 0.f, 0.f, 0.f);
        if (gn >= 0 && gn + 3 < NN) {
            v = *reinterpret_cast<const float4*>(&Xb[(size_t)i * NN + gn]);
            float me = meB_sh[i];
            float4 mk = *reinterpret_cast<const float4*>(&mkB[gn]);
            v.x = (v.x - me) * mk.x;
            v.y = (v.y - me) * mk.y;
            v.z = (v.z - me) * mk.z;
            v.w = (v.w - me) * mk.w;
        }
        fs[t * 4 + 0][i] = v.x;
        fs[t * 4 + 1][i] = v.y;
        fs[t * 4 + 2][i] = v.z;
        fs[t * 4 + 3][i] = v.w;
    }
    __syncthreads();
    // pass 2: per-column sums over 128 channels -> inv
    if (tid < 192) {
        int row = tid % 48, seg = tid / 48;
        float ss = 0.f;
#pragma unroll
        for (int i = 0; i < 32; ++i) { float v = fs[row][seg * 32 + i]; ss += v * v; }
        ps[row][seg] = ss;
    }
    __syncthreads();
    if (tid < 48) invc[tid] = rsqrtf(ps[tid][0] + ps[tid][1] + ps[tid][2] + ps[tid][3] + 0.001f);
    __syncthreads();
    // pass 3: relu(v*inv), hi/lo pack with XOR swizzle
    for (int e = tid; e < 128 * 12; e += 256) {
        int i = e / 12, t = e - i * 12;
#pragma unroll
        for (int j = 0; j < 4; ++j) {
            int row = t * 4 + j;
            float v = fmaxf(fs[row][i] * invc[row], 0.f);
            int col = i ^ ((row & 7) << 3);
            unsigned short h = f2bf(v);
            xh[row][col] = h;
            xl[row][col] = f2bf(v - bf2f(h));
        }
    }
    __syncthreads();

    int wid = tid >> 6, lane = tid & 63;
    int i32 = wid & 1, kh = wid >> 1;
    int r = lane & 15, g = lane >> 4;
    size_t brW = (size_t)br * (CH / 32) * (1152 / 32) * 1024;

    f32x4 acc[2][2] = {};
#pragma unroll 3
    for (int t = 0; t < 18; ++t) {
        int k = t >> 1, s = kh * 2 + (t & 1);
        int q32 = k * 4 + s;
        size_t widx = brW + ((size_t)(i32 * 36 + q32)) * 1024 + lane * 8;
        bf16x8 ah[2], al[2];
        ah[0] = *reinterpret_cast<const bf16x8*>(&Wh[widx]);
        ah[1] = *reinterpret_cast<const bf16x8*>(&Wh[widx + 512]);
        al[0] = *reinterpret_cast<const bf16x8*>(&Wl[widx]);
        al[1] = *reinterpret_cast<const bf16x8*>(&Wl[widx + 512]);
        bf16x8 bh[2], bl[2];
#pragma unroll
        for (int fn = 0; fn < 2; ++fn) {
            int row = fn * 16 + r + k;
            int chs = (s * 32 + g * 8) ^ ((row & 7) << 3);
            bh[fn] = *reinterpret_cast<const bf16x8*>(&xh[row][chs]);
            bl[fn] = *reinterpret_cast<const bf16x8*>(&xl[row][chs]);
        }
#pragma unroll
        for (int fc = 0; fc < 2; ++fc)
#pragma unroll
            for (int fn = 0; fn < 2; ++fn) {
                acc[fc][fn] = __builtin_amdgcn_mfma_f32_16x16x32_bf16(ah[fc], bh[fn], acc[fc][fn], 0, 0, 0);
                acc[fc][fn] = __builtin_amdgcn_mfma_f32_16x16x32_bf16(al[fc], bh[fn], acc[fc][fn], 0, 0, 0);
                acc[fc][fn] = __builtin_amdgcn_mfma_f32_16x16x32_bf16(ah[fc], bl[fn], acc[fc][fn], 0, 0, 0);
            }
    }

    if (kh == 1) {
#pragma unroll
        for (int fc = 0; fc < 2; ++fc)
#pragma unroll
            for (int fn = 0; fn < 2; ++fn)
#pragma unroll
                for (int rr = 0; rr < 4; ++rr)
                    red2[i32][fc * 16 + 4 * g + rr][fn * 16 + r] = acc[fc][fn][rr];
    }
    __syncthreads();
    if (kh == 0) {
        float* Outp = (br ? T1p : T0) + (size_t)b * CH * NN;
#pragma unroll
        for (int fc = 0; fc < 2; ++fc)
#pragma unroll
            for (int fn = 0; fn < 2; ++fn) {
                int n = n0 + fn * 16 + r;
#pragma unroll
                for (int rr = 0; rr < 4; ++rr) {
                    int irow = fc * 16 + 4 * g + rr;
                    float v = acc[fc][fn][rr] + red2[i32][irow][fn * 16 + r];
                    Outp[(size_t)(i32 * 32 + irow) * NN + n] = v;
                    if (br == 1) {
                        int cg = i32 * 32 + irow;
                        int chunk = ((b * 2 + (cg >> 5)) * 32 + (n >> 5)) * 2 + ((cg >> 4) & 1);
                        int lane2 = ((n >> 3) & 3) * 16 + (cg & 15);
                        T1pk[((size_t)chunk * 64 + lane2) * 8 + (n & 7)] = f2bf(v);
                    }
                }
            }
    }
}

// ---------------- fused CH matL: Zcur -= H*mask*(T0 + T1p@L) ----------------
// grid (NN/32, 1, BB); block 64c x 32n; waves: kh x c-half.
__global__ __launch_bounds__(256) void k_matL_ch(const unsigned short* __restrict__ T1pk,
                                                 const unsigned short* __restrict__ Wpk,
                                                 const float* __restrict__ T1p,
                                                 const float* __restrict__ Wsum,
                                                 const float* __restrict__ mask,
                                                 const float* __restrict__ T0,
                                                 float* __restrict__ Zcur) {
    __shared__ float red2[2][32][33];
    int nt32 = blockIdx.x;
    int b = blockIdx.z;
    int tid = threadIdx.x;
    int wid = tid >> 6, lane = tid & 63;
    int kh = wid >> 1, ch = wid & 1;
    int r = lane & 15, g = lane >> 4;
    const unsigned short* Xb = T1pk + ((size_t)(b * 2 + ch)) * 32768 + (size_t)lane * 8;
    const unsigned short* Wb = Wpk + ((size_t)(b * 32 + nt32)) * 32768 + (size_t)lane * 8;

    f32x4 acc[2][2] = {};
#pragma unroll 4
    for (int ms = kh * 16; ms < kh * 16 + 16; ++ms) {
        bf16x8 a0 = *reinterpret_cast<const bf16x8*>(&Xb[(size_t)ms * 1024]);
        bf16x8 a1 = *reinterpret_cast<const bf16x8*>(&Xb[(size_t)ms * 1024 + 512]);
        bf16x8 w0 = *reinterpret_cast<const bf16x8*>(&Wb[(size_t)ms * 1024]);
        bf16x8 w1 = *reinterpret_cast<const bf16x8*>(&Wb[(size_t)ms * 1024 + 512]);
        acc[0][0] = __builtin_amdgcn_mfma_f32_16x16x32_bf16(a0, w0, acc[0][0], 0, 0, 0);
        acc[0][1] = __builtin_amdgcn_mfma_f32_16x16x32_bf16(a0, w1, acc[0][1], 0, 0, 0);
        acc[1][0] = __builtin_amdgcn_mfma_f32_16x16x32_bf16(a1, w0, acc[1][0], 0, 0, 0);
        acc[1][1] = __builtin_amdgcn_mfma_f32_16x16x32_bf16(a1, w1, acc[1][1], 0, 0, 0);
    }
    if (kh == 1) {
#pragma unroll
        for (int fc = 0; fc < 2; ++fc)
#pragma unroll
            for (int fn = 0; fn < 2; ++fn)
#pragma unroll
                for (int rr = 0; rr < 4; ++rr)
                    red2[ch][fc * 16 + 4 * g + rr][fn * 16 + r] = acc[fc][fn][rr];
    }
    __syncthreads();
    if (kh == 0) {
        const float* T1b = T1p + (size_t)b * CH * NN;
        const float* T0b = T0 + (size_t)b * CH * NN;
        float* Zb = Zcur + (size_t)b * CH * NN;
        const float* mk = mask + b * NN;
        const float* wsB = Wsum + b * NN;
#pragma unroll
        for (int fc = 0; fc < 2; ++fc)
#pragma unroll
            for (int fn = 0; fn < 2; ++fn) {
                int ncol = nt32 * 32 + fn * 16 + r;
                float mkv = mk[ncol], wsv = wsB[ncol];
#pragma unroll
                for (int rr = 0; rr < 4; ++rr) {
                    int crow = ch * 32 + fc * 16 + 4 * g + rr;
                    float v = acc[fc][fn][rr] + red2[ch][fc * 16 + 4 * g + rr][fn * 16 + r];
                    float y = T1b[(size_t)crow * NN + ncol] * wsv - v;
                    size_t zi = (size_t)crow * NN + ncol;
                    Zb[zi] = Zb[zi] - HSTEP * mkv * (T0b[zi] + y);
                }
            }
    }
}

// ---------------- close ----------------
__global__ __launch_bounds__(256) void k_close(const float* __restrict__ Zcur,
                                               const float* __restrict__ Kcl,
                                               const float* __restrict__ mask,
                                               float* __restrict__ Zout) {
    __shared__ float red[4][64][COUT];
    int tid = threadIdx.x;
    int nl = tid & 63, cg = tid >> 6;
    int n = blockIdx.x * 64 + nl;
    int b = blockIdx.y;
    float acc[COUT] = {};
#pragma unroll
    for (int cc = 0; cc < 16; ++cc) {
        int c = cg * 16 + cc;
        float zv = Zcur[((size_t)b * CH + c) * NN + n];
#pragma unroll
        for (int o = 0; o < COUT; ++o) acc[o] += Kcl[o * CH + c] * zv;
    }
#pragma unroll
    for (int o = 0; o < COUT; ++o) red[cg][nl][o] = acc[o];
    __syncthreads();
    if (cg == 0) {
        float mv = mask[b * NN + n];
#pragma unroll
        for (int o = 0; o < COUT; ++o) {
            float s = red[0][nl][o] + red[1][nl][o] + red[2][nl][o] + red[3][nl][o];
            Zout[((size_t)b * COUT + o) * NN + n] = s * mv;
        }
    }
}

// ---------------- center3 ----------------
__global__ __launch_bounds__(256) void k_center3(const float* __restrict__ Zout, float* __restrict__ Zc3) {
    __shared__ float red[256];
    int c = blockIdx.x, b = blockIdx.y, tid = threadIdx.x;
    const float* src = Zout + ((size_t)b * COUT + c) * NN;
    float s = 0.f;
    for (int n = tid; n < NN; n += 256) s += src[n];
    float mean = blockSum(s, red) / (float)NN;
    float* dst = Zc3 + ((size_t)b * COUT + c) * NN;
    for (int n = tid; n < NN; n += 256) dst[n] = src[n] - mean;
}

// ---------------- final pairwise distances ----------------
__global__ __launch_bounds__(256) void k_dist(const float* __restrict__ Zc3,
                                              float* __restrict__ dout) {
    __shared__ float Ai[3][64], Aj[3][64], ni[64], nj[64];
    int bg = blockIdx.z;
    int b = bg / 3, g = bg - 3 * b;
    int i0 = blockIdx.x * 64, j0 = blockIdx.y * 64;
    int tid = threadIdx.x;
    for (int e = tid; e < 192; e += 256) {
        int c = e / 64, t = e - c * 64;
        Ai[c][t] = Zc3[((size_t)b * COUT + g * 3 + c) * NN + i0 + t];
    }
    for (int e = tid; e < 192; e += 256) {
        int c = e / 64, t = e - c * 64;
        Aj[c][t] = Zc3[((size_t)b * COUT + g * 3 + c) * NN + j0 + t];
    }
    __syncthreads();
    if (tid < 64) {
        ni[tid] = Ai[0][tid] * Ai[0][tid] + Ai[1][tid] * Ai[1][tid] + Ai[2][tid] * Ai[2][tid];
    } else if (tid < 128) {
        int t = tid - 64;
        nj[t] = Aj[0][t] * Aj[0][t] + Aj[1][t] * Aj[1][t] + Aj[2][t] * Aj[2][t];
    }
    __syncthreads();
    int tx = tid & 15, ty = tid >> 4;
    for (int q = 0; q < 4; ++q) {
        int i = ty * 4 + q;
        float a0 = Ai[0][i], a1 = Ai[1][i], a2 = Ai[2][i], n2i = ni[i];
        float res[4];
#pragma unroll
        for (int r = 0; r < 4; ++r) {
            int j = tx * 4 + r;
            float D = n2i + nj[j] - 2.f * (a0 * Aj[0][j] + a1 * Aj[1][j] + a2 * Aj[2][j]);
            D = fmaxf(D, 0.f);
            res[r] = (D > 0.f) ? sqrtf(D) : 0.f;
        }
        *reinterpret_cast<float4*>(&dout[(((size_t)b * 3 + g) * NN + i0 + i) * NN + j0 + tx * 4]) =
            *reinterpret_cast<float4*>(res);
    }
}

// ---------------- driver ----------------
extern "C" void kernel_launch(void* const* d_in, const int* in_sizes, int n_in,
                              void* d_out, int out_size, void* d_ws, size_t ws_size,
                              hipStream_t stream) {
    (void)in_sizes; (void)n_in; (void)out_size; (void)ws_size;
    const float* Zin  = (const float*)d_in[0];
    const float* mask = (const float*)d_in[1];
    const float* Kop  = (const float*)d_in[2];
    const float* Kcl  = (const float*)d_in[3];
    const float* Win  = (const float*)d_in[4];
    const float* Bias = (const float*)d_in[5];
    float* out = (float*)d_out;
    float* ws = (float*)d_ws;

    size_t off = 0;
    float* Zcur = ws + off;  off += (size_t)BB * CH * NN;
    float* C0   = ws + off;  off += (size_t)BB * CC * NN;
    float* C1   = ws + off;  off += (size_t)BB * CC * NN;
    float* A1   = ws + off;  off += (size_t)BB * CC * NN;
    float* T0   = ws + off;  off += (size_t)BB * CH * NN;
    float* T1p  = ws + off;  off += (size_t)BB * CH * NN;
    float* Za   = ws + off;  off += (size_t)BB * 65 * NN;
    float* Wsum = ws + off;  off += (size_t)BB * NN;
    float* bks  = ws + off;  off += (size_t)NL * 2 * CC * KS;
    float* Zc3  = ws + off;  off += (size_t)BB * COUT * NN;
    float* meanP0 = ws + off; off += (size_t)BB * CC * 16;
    float* meanP1 = ws + off; off += (size_t)BB * CC * 32;
    float* msum = ws + off;  off += (size_t)BB;

    // Scratch in the (as-yet-unwritten) dists region of d_out (25,165,824 floats):
    unsigned short* Wpk2  = (unsigned short*)(out + (size_t)4194304);    // [.. 8,388,608)
    unsigned short* C1pk  = (unsigned short*)(out + (size_t)8388608);    // 1,048,576 shorts
    unsigned short* T1pk  = (unsigned short*)(out + (size_t)8912896);    // 524,288 shorts
    unsigned short* PKc_h = (unsigned short*)(out + (size_t)14680064);
    unsigned short* PKc_l = (unsigned short*)(out + (size_t)15417344);
    unsigned short* PKt_h = (unsigned short*)(out + (size_t)16154624);
    unsigned short* PKt_l = (unsigned short*)(out + (size_t)16891904);   // ends 17,629,184

    const int wtot = NL * 2 * CC * CH * KS;
    k_prep_wbf<<<dim3((wtot + 255) / 256), 256, 0, stream>>>(Win, PKc_h, PKc_l, PKt_h, PKt_l);
    k_prep_bks<<<dim3((NL * 2 * CC * KS + 255) / 256), 256, 0, stream>>>(Win, Bias, bks);
    k_zero<<<dim3(BB * NN / 256), 256, 0, stream>>>(Wsum, BB * NN);
    k_msum<<<dim3(BB), 256, 0, stream>>>(mask, msum);
    k_open<<<dim3(NN / 256, CH, BB), 256, 0, stream>>>(Zin, mask, Kop, Zcur);
    k_za<<<dim3(65, BB), 256, 0, stream>>>(Zcur, mask, Za);
    k_gramW<<<dim3(16, 16, BB), 256, 0, stream>>>(Za, mask, Wpk2, Wsum);

    for (int l = 0; l < NL; ++l) {
        const unsigned short* PKc_h_l = PKc_h + (size_t)l * 2 * CC * 576;
        const unsigned short* PKc_l_l = PKc_l + (size_t)l * 2 * CC * 576;
        const unsigned short* PKt_h_l = PKt_h + (size_t)l * 2 * CH * 1152;
        const unsigned short* PKt_l_l = PKt_l + (size_t)l * 2 * CH * 1152;
        const float* bksl = bks + (size_t)l * 2 * CC * KS;

        k_conv1_mfma<<<dim3(NN / 64, 4, BB), 256, 0, stream>>>(
            Zcur, PKc_h_l, PKc_l_l, bksl, mask, C0, C1, C1pk, meanP0);
        k_matL_cc<<<dim3(NN / 32, 1, BB * 2), 256, 0, stream>>>(
            C1pk, Wpk2, C1, Wsum, mask, A1, meanP1);
        k_convT_mfma<<<dim3(NN / 32, 2, BB), 256, 0, stream>>>(
            C0, A1, PKt_h_l, PKt_l_l, mask, meanP0, meanP1, msum, T0, T1p, T1pk);
        k_matL_ch<<<dim3(NN / 32, 1, BB), 256, 0, stream>>>(
            T1pk, Wpk2, T1p, Wsum, mask, T0, Zcur);
    }

    float* Zout = out + (size_t)BB * 3 * NN * NN;
    k_close<<<dim3(NN / 64, BB), 256, 0, stream>>>(Zcur, Kcl, mask, Zout);
    k_center3<<<dim3(COUT, BB), 256, 0, stream>>>(Zout, Zc3);
    k_dist<<<dim3(16, 16, 3 * BB), 256, 0, stream>>>(Zc3, out);
}